// Round 4
// baseline (214.490 us; speedup 1.0000x reference)
//
#include <hip/hip_runtime.h>
#include <hip/hip_bf16.h>

// Problem constants: B=4, C=64, O=64, H=W=128, K=3, PAD=1
#define BB 4
#define CC 64
#define OO 64
#define HH 128
#define WW 128
#define HW (HH * WW)       // 16384
#define K2 9
#define OCOFF 18           // 2*K2 offset channels

typedef __attribute__((ext_vector_type(8))) short short8;     // 8 bf16 = 4 VGPR
typedef __attribute__((ext_vector_type(16))) float f32x16;    // MFMA 32x32 acc

// RNE float->bf16 (bits), plus residual ("lo") term. Finite inputs only.
__device__ __forceinline__ unsigned short bf16_rne(float v) {
  unsigned u = __builtin_bit_cast(unsigned, v);
  return (unsigned short)((u + 0x7FFFu + ((u >> 16) & 1u)) >> 16);
}
__device__ __forceinline__ void bf16_split(float v, unsigned short& hi, unsigned short& lo) {
  hi = bf16_rne(v);
  float hf = __builtin_bit_cast(float, (unsigned)hi << 16);
  lo = bf16_rne(v - hf);
}

// ---------------------------------------------------------------------------
// prep: offset-conv weights  Wo[c][k][oc]  from w_off[oc][c][k]
// ---------------------------------------------------------------------------
__global__ __launch_bounds__(256) void prep_wo(
    const float* __restrict__ w_off, float* __restrict__ Wo) {
  int idx = blockIdx.x * 256 + threadIdx.x;
  if (idx < CC * K2 * OCOFF) {            // 10368
    int oc = idx % OCOFF;
    int ck = idx / OCOFF;                 // c*9 + k
    Wo[idx] = w_off[oc * (CC * K2) + ck];
  }
}

// ---------------------------------------------------------------------------
// prep: main weights -> MFMA A-fragment-linear hi/lo bf16.
// dword index d = c*4096 + ((m*8 + s*2 + hh)*64 + l)*4 + j2
//   c = tap(0..8), m = o-tile(0..1), s = kstep(0..3), hh = hi/lo,
//   l = lane(0..63), j2 = dword within lane row (j = 2*j2, 2*j2+1)
// value: A[o = m*32 + (l&31)][ch = s*16 + (l>>5)*8 + j] = weight[o][ch][c]
// ---------------------------------------------------------------------------
__global__ __launch_bounds__(256) void prep_wfrag(
    const float* __restrict__ weight, unsigned* __restrict__ wf) {
  int d = blockIdx.x * 256 + threadIdx.x;
  if (d >= 9 * 4096) return;
  int j2 = d & 3, l = (d >> 2) & 63, hh = (d >> 8) & 1, s = (d >> 9) & 3,
      m = (d >> 11) & 1, c = d >> 12;
  int o = m * 32 + (l & 31);
  int g = l >> 5;
  int ch0 = s * 16 + g * 8 + j2 * 2;
  float v0 = weight[(o * 64 + ch0) * 9 + c];
  float v1 = weight[(o * 64 + ch0 + 1) * 9 + c];
  unsigned short h0, l0, h1, l1;
  bf16_split(v0, h0, l0);
  bf16_split(v1, h1, l1);
  unsigned short b0 = hh ? l0 : h0;
  unsigned short b1 = hh ? l1 : h1;
  wf[d] = (unsigned)b0 | ((unsigned)b1 << 16);
}

// ---------------------------------------------------------------------------
// NCHW -> NHWC transpose: x_t[b][h][w][c]
// ---------------------------------------------------------------------------
__global__ __launch_bounds__(256) void transpose_x(
    const float* __restrict__ x, float* __restrict__ xt) {
  __shared__ float tile[64][33];
  int blk = blockIdx.x;
  int wt = blk & 3, h = (blk >> 2) & 127, b = blk >> 9;
  int w0 = wt * 32;
  int t = threadIdx.x;
  {
    int w_l = t & 31, c_l = t >> 5;          // c_l 0..7
#pragma unroll
    for (int i = 0; i < 8; ++i) {
      int cc = c_l * 8 + i;
      tile[cc][w_l] = x[(((size_t)b * 64 + cc) * 128 + h) * 128 + w0 + w_l];
    }
  }
  __syncthreads();
  {
    int c_w = t & 63, w_w = t >> 6;          // w_w 0..3
#pragma unroll
    for (int i = 0; i < 8; ++i) {
      int wl = w_w * 8 + i;
      xt[(((size_t)b * 128 + h) * 128 + w0 + wl) * 64 + c_w] = tile[c_w][wl];
    }
  }
}

// ---------------------------------------------------------------------------
// offset conv (fp32, audited): offs[b][oc][h][w], oc in 0..17.
// ---------------------------------------------------------------------------
__global__ __launch_bounds__(256) void offset_conv(
    const float* __restrict__ x, const float* __restrict__ Wo,
    const float* __restrict__ b_off, float* __restrict__ offs) {
  int sx = (blockIdx.x & 7) * 32 + (blockIdx.x >> 3);   // XCD-bijective swizzle
  int p = sx * 256 + threadIdx.x;
  int w = p & (WW - 1);
  int h = (p >> 7) & (HH - 1);
  int b = p >> 14;
  int oc0 = blockIdx.y * 9;

  float acc[9];
#pragma unroll
  for (int i = 0; i < 9; ++i) acc[i] = b_off[oc0 + i];

  const float* xb = x + (size_t)b * CC * HW;

#pragma unroll
  for (int ky = 0; ky < 3; ++ky) {
    int y = h + ky - 1;
#pragma unroll
    for (int kx = 0; kx < 3; ++kx) {
      int xx = w + kx - 1;
      bool v = ((unsigned)y < (unsigned)HH) && ((unsigned)xx < (unsigned)WW);
      float vf = v ? 1.0f : 0.0f;
      int yc = min(max(y, 0), HH - 1);
      int xc = min(max(xx, 0), WW - 1);
      const float* xp = xb + yc * WW + xc;
      const int kk = ky * 3 + kx;
      const float* wp = Wo + kk * OCOFF + oc0;
#pragma unroll 4
      for (int c = 0; c < CC; ++c) {
        float xv = xp[(size_t)c * HW] * vf;
        const float* wc = wp + c * (K2 * OCOFF);   // wave-uniform address
#pragma unroll
        for (int i = 0; i < 9; ++i) acc[i] = fmaf(xv, wc[i], acc[i]);
      }
    }
  }

  float* op = offs + (((size_t)b * OCOFF + oc0) * HH + h) * WW + w;
#pragma unroll
  for (int i = 0; i < 9; ++i) op[(size_t)i * HW] = acc[i];
}

// ---------------------------------------------------------------------------
// deform conv via MFMA: out[o][p] = sum_{c,k} W[o][ck] * S[ck][p] + bias.
// Block = 128 px (one b,h row), 4 waves x 32 px. Wave: 32 px x all 64 o.
// K-order: tap-major (K = tap*64 + ch). Per tap: sample 64 ch for own px
// directly into B-frag lanes (lane l: px=l&31, ch octet (l>>5)*8), hi/lo
// split, 24 mfma_32x32x16_bf16 (2 o-tiles x 4 ksteps x 3 hi/lo terms).
// W staged fragment-linear in LDS, double-buffered.
// ---------------------------------------------------------------------------
__global__ __launch_bounds__(256, 2) void deform_mfma(
    const float* __restrict__ xt, const float* __restrict__ offs,
    const unsigned* __restrict__ wfrag, const float* __restrict__ bias,
    float* __restrict__ out) {
  __shared__ unsigned wlds[2][4096];    // 2 x 16KB

  const int swz = (blockIdx.x & 7) * 64 + (blockIdx.x >> 3);  // 512 = 8*64
  const int h = swz & 127, b = swz >> 7;
  const int tid = threadIdx.x;
  const int l = tid & 63, wv = tid >> 6;
  const int P = l & 31, g = l >> 5;
  const int wpix = wv * 32 + P;

  f32x16 acc0 = {0,0,0,0,0,0,0,0,0,0,0,0,0,0,0,0};
  f32x16 acc1 = {0,0,0,0,0,0,0,0,0,0,0,0,0,0,0,0};

  // prologue: stage chunk 0 into buf 0 (reg-staged, linear, conflict-free)
  {
    const uint4* gs = (const uint4*)(wfrag);
#pragma unroll
    for (int i = 0; i < 4; ++i) {
      uint4 t4 = gs[(wv * 4 + i) * 64 + l];
      *(uint4*)&wlds[0][((wv * 4 + i) * 64 + l) * 4] = t4;
    }
  }
  __syncthreads();

  const float* ob = offs + ((size_t)b * OCOFF) * HW + h * WW;  // + oc*HW + wpix

#pragma unroll 1
  for (int c = 0; c < 9; ++c) {
    const int buf = c & 1;

    // issue next W chunk's loads early (latency hides under sampling)
    uint4 stg[4];
    if (c < 8) {
      const uint4* gs = (const uint4*)(wfrag + (size_t)(c + 1) * 4096);
#pragma unroll
      for (int i = 0; i < 4; ++i) stg[i] = gs[(wv * 4 + i) * 64 + l];
    }

    // ---- sampling: this wave's 32 px, all 64 ch, tap c ----
    const int dy = c / 3 - 1, dx = c % 3 - 1;
    float oy = ob[(size_t)(2 * c) * HW + wpix];
    float ox = ob[(size_t)(2 * c + 1) * HW + wpix];
    float py = oy + (float)(h + dy);
    float px = ox + (float)(wpix + dx);
    float y0f = floorf(py), x0f = floorf(px);
    float wy1 = py - y0f, wx1 = px - x0f;
    float wy0 = 1.0f - wy1, wx0 = 1.0f - wx1;
    int y0 = (int)y0f, x0 = (int)x0f;
    int y1 = y0 + 1, x1 = x0 + 1;
    bool vy0 = (unsigned)y0 < (unsigned)HH, vy1 = (unsigned)y1 < (unsigned)HH;
    bool vx0 = (unsigned)x0 < (unsigned)WW, vx1 = (unsigned)x1 < (unsigned)WW;
    float w00 = (vy0 && vx0) ? wy0 * wx0 : 0.0f;
    float w01 = (vy0 && vx1) ? wy0 * wx1 : 0.0f;
    float w10 = (vy1 && vx0) ? wy1 * wx0 : 0.0f;
    float w11 = (vy1 && vx1) ? wy1 * wx1 : 0.0f;
    int y0c = min(max(y0, 0), HH - 1), y1c = min(max(y1, 0), HH - 1);
    int x0c = min(max(x0, 0), WW - 1), x1c = min(max(x1, 0), WW - 1);
    const float* e00 = xt + (((size_t)b * 128 + y0c) * 128 + x0c) * 64;
    const float* e01 = xt + (((size_t)b * 128 + y0c) * 128 + x1c) * 64;
    const float* e10 = xt + (((size_t)b * 128 + y1c) * 128 + x0c) * 64;
    const float* e11 = xt + (((size_t)b * 128 + y1c) * 128 + x1c) * 64;

    short8 SH[4], SL[4];
#pragma unroll
    for (int s = 0; s < 4; ++s) {
      const int cb = s * 16 + g * 8;   // lane's channel base for this kstep
      float4 a0 = *(const float4*)(e00 + cb), a1 = *(const float4*)(e00 + cb + 4);
      float4 b0 = *(const float4*)(e01 + cb), b1 = *(const float4*)(e01 + cb + 4);
      float4 c0 = *(const float4*)(e10 + cb), c1 = *(const float4*)(e10 + cb + 4);
      float4 d0 = *(const float4*)(e11 + cb), d1 = *(const float4*)(e11 + cb + 4);
      float v[8];
      v[0] = fmaf(w00, a0.x, fmaf(w01, b0.x, fmaf(w10, c0.x, w11 * d0.x)));
      v[1] = fmaf(w00, a0.y, fmaf(w01, b0.y, fmaf(w10, c0.y, w11 * d0.y)));
      v[2] = fmaf(w00, a0.z, fmaf(w01, b0.z, fmaf(w10, c0.z, w11 * d0.z)));
      v[3] = fmaf(w00, a0.w, fmaf(w01, b0.w, fmaf(w10, c0.w, w11 * d0.w)));
      v[4] = fmaf(w00, a1.x, fmaf(w01, b1.x, fmaf(w10, c1.x, w11 * d1.x)));
      v[5] = fmaf(w00, a1.y, fmaf(w01, b1.y, fmaf(w10, c1.y, w11 * d1.y)));
      v[6] = fmaf(w00, a1.z, fmaf(w01, b1.z, fmaf(w10, c1.z, w11 * d1.z)));
      v[7] = fmaf(w00, a1.w, fmaf(w01, b1.w, fmaf(w10, c1.w, w11 * d1.w)));
      short8 sh, sl;
#pragma unroll
      for (int j = 0; j < 8; ++j) {
        unsigned short hb, lb;
        bf16_split(v[j], hb, lb);
        sh[j] = (short)hb;
        sl[j] = (short)lb;
      }
      SH[s] = sh;
      SL[s] = sl;
    }

    // write-late: next W chunk into the other buffer
    if (c < 8) {
#pragma unroll
      for (int i = 0; i < 4; ++i)
        *(uint4*)&wlds[buf ^ 1][((wv * 4 + i) * 64 + l) * 4] = stg[i];
    }

    // ---- MFMA: D[o][px] += W * S, hi/lo 3-term ----
#pragma unroll
    for (int s = 0; s < 4; ++s) {
      short8 wh0 = *(const short8*)&wlds[buf][((0 * 8 + s * 2 + 0) * 64 + l) * 4];
      short8 wl0 = *(const short8*)&wlds[buf][((0 * 8 + s * 2 + 1) * 64 + l) * 4];
      short8 wh1 = *(const short8*)&wlds[buf][((1 * 8 + s * 2 + 0) * 64 + l) * 4];
      short8 wl1 = *(const short8*)&wlds[buf][((1 * 8 + s * 2 + 1) * 64 + l) * 4];
      acc0 = __builtin_amdgcn_mfma_f32_32x32x16_bf16(wh0, SH[s], acc0, 0, 0, 0);
      acc0 = __builtin_amdgcn_mfma_f32_32x32x16_bf16(wh0, SL[s], acc0, 0, 0, 0);
      acc0 = __builtin_amdgcn_mfma_f32_32x32x16_bf16(wl0, SH[s], acc0, 0, 0, 0);
      acc1 = __builtin_amdgcn_mfma_f32_32x32x16_bf16(wh1, SH[s], acc1, 0, 0, 0);
      acc1 = __builtin_amdgcn_mfma_f32_32x32x16_bf16(wh1, SL[s], acc1, 0, 0, 0);
      acc1 = __builtin_amdgcn_mfma_f32_32x32x16_bf16(wl1, SH[s], acc1, 0, 0, 0);
    }
    __syncthreads();
  }

  // epilogue: bias + store. D layout (32x32): col=lane&31, row=(r&3)+8*(r>>2)+4*g.
#pragma unroll
  for (int r = 0; r < 16; ++r) {
    int o0 = (r & 3) + 8 * (r >> 2) + 4 * g;
    out[(((size_t)b * 64 + o0) * 128 + h) * 128 + wpix] = acc0[r] + bias[o0];
    int o1 = 32 + o0;
    out[(((size_t)b * 64 + o1) * 128 + h) * 128 + wpix] = acc1[r] + bias[o1];
  }
}

// ---------------------------------------------------------------------------
extern "C" void kernel_launch(void* const* d_in, const int* in_sizes, int n_in,
                              void* d_out, int out_size, void* d_ws, size_t ws_size,
                              hipStream_t stream) {
  const float* x      = (const float*)d_in[0];
  const float* w_off  = (const float*)d_in[1];
  const float* b_off  = (const float*)d_in[2];
  const float* weight = (const float*)d_in[3];
  const float* bias   = (const float*)d_in[4];
  float* out = (float*)d_out;

  // workspace (floats): xt | offs | Wo | wfrag   (~21.7 MB)
  float*    xt    = (float*)d_ws;                  // 4*128*128*64 = 4,194,304
  float*    offs  = xt + (size_t)4194304;          // 4*18*16384   = 1,179,648
  float*    Wo    = offs + (size_t)1179648;        // 10,368
  unsigned* wfrag = (unsigned*)(Wo + 10368);       // 36,864 dwords

  prep_wo<<<41, 256, 0, stream>>>(w_off, Wo);
  prep_wfrag<<<144, 256, 0, stream>>>(weight, wfrag);
  transpose_x<<<2048, 256, 0, stream>>>(x, xt);

  dim3 gridOff(256, 2);
  offset_conv<<<gridOff, 256, 0, stream>>>(x, Wo, b_off, offs);

  deform_mfma<<<512, 256, 0, stream>>>(xt, offs, wfrag, bias, out);
}

// Round 5
// 180.126 us; speedup vs baseline: 1.1908x; 1.1908x over previous
//
#include <hip/hip_runtime.h>
#include <hip/hip_bf16.h>

// Problem constants: B=4, C=64, O=64, H=W=128, K=3, PAD=1
#define BB 4
#define CC 64
#define OO 64
#define HH 128
#define WW 128
#define HW (HH * WW)       // 16384
#define K2 9
#define OCOFF 18           // 2*K2 offset channels

typedef __attribute__((ext_vector_type(8))) short short8;     // 8 bf16 = 4 VGPR
typedef __attribute__((ext_vector_type(16))) float f32x16;    // MFMA 32x32 acc

// RNE float->bf16 (bits), plus residual ("lo") term. Finite inputs only.
__device__ __forceinline__ unsigned short bf16_rne(float v) {
  unsigned u = __builtin_bit_cast(unsigned, v);
  return (unsigned short)((u + 0x7FFFu + ((u >> 16) & 1u)) >> 16);
}
__device__ __forceinline__ void bf16_split(float v, unsigned short& hi, unsigned short& lo) {
  hi = bf16_rne(v);
  float hf = __builtin_bit_cast(float, (unsigned)hi << 16);
  lo = bf16_rne(v - hf);
}
__device__ __forceinline__ float4 ld4(const float* p) { return *(const float4*)p; }

// ---------------------------------------------------------------------------
// prep: main weights -> MFMA A-fragment-linear hi/lo bf16. (validated r4)
// dword d = ((c*16 + m*8 + s*2 + hh)*64 + l)*4 + j2
// value: A[o = m*32 + (l&31)][ch = s*16 + (l>>5)*8 + j] = weight[o][ch][c]
// ---------------------------------------------------------------------------
__global__ __launch_bounds__(256) void prep_wfrag(
    const float* __restrict__ weight, unsigned* __restrict__ wf) {
  int d = blockIdx.x * 256 + threadIdx.x;
  if (d >= 9 * 4096) return;
  int j2 = d & 3, l = (d >> 2) & 63, hh = (d >> 8) & 1, s = (d >> 9) & 3,
      m = (d >> 11) & 1, c = d >> 12;
  int o = m * 32 + (l & 31);
  int g = l >> 5;
  int ch0 = s * 16 + g * 8 + j2 * 2;
  float v0 = weight[(o * 64 + ch0) * 9 + c];
  float v1 = weight[(o * 64 + ch0 + 1) * 9 + c];
  unsigned short h0, l0, h1, l1;
  bf16_split(v0, h0, l0);
  bf16_split(v1, h1, l1);
  unsigned short b0 = hh ? l0 : h0;
  unsigned short b1 = hh ? l1 : h1;
  wf[d] = (unsigned)b0 | ((unsigned)b1 << 16);
}

// ---------------------------------------------------------------------------
// prep: offset-conv weights -> A-fragments (rows 0..17 = oc, 18..31 zero).
// dword d = ((c*8 + s*2 + hh)*64 + l)*4 + j2
// ---------------------------------------------------------------------------
__global__ __launch_bounds__(256) void prep_wofrag(
    const float* __restrict__ w_off, unsigned* __restrict__ wof) {
  int d = blockIdx.x * 256 + threadIdx.x;
  if (d >= 9 * 2048) return;
  int j2 = d & 3, l = (d >> 2) & 63, hh = (d >> 8) & 1, s = (d >> 9) & 3,
      c = d >> 11;
  int oc = l & 31;
  int g = l >> 5;
  int ch0 = s * 16 + g * 8 + j2 * 2;
  unsigned r = 0;
  if (oc < OCOFF) {
    float v0 = w_off[(oc * 64 + ch0) * 9 + c];
    float v1 = w_off[(oc * 64 + ch0 + 1) * 9 + c];
    unsigned short h0, l0, h1, l1;
    bf16_split(v0, h0, l0);
    bf16_split(v1, h1, l1);
    unsigned short b0 = hh ? l0 : h0;
    unsigned short b1 = hh ? l1 : h1;
    r = (unsigned)b0 | ((unsigned)b1 << 16);
  }
  wof[d] = r;
}

// ---------------------------------------------------------------------------
// NCHW -> NHWC transpose: x_t[b][h][w][c]   (validated r4)
// ---------------------------------------------------------------------------
__global__ __launch_bounds__(256) void transpose_x(
    const float* __restrict__ x, float* __restrict__ xt) {
  __shared__ float tile[64][33];
  int blk = blockIdx.x;
  int wt = blk & 3, h = (blk >> 2) & 127, b = blk >> 9;
  int w0 = wt * 32;
  int t = threadIdx.x;
  {
    int w_l = t & 31, c_l = t >> 5;
#pragma unroll
    for (int i = 0; i < 8; ++i) {
      int cc = c_l * 8 + i;
      tile[cc][w_l] = x[(((size_t)b * 64 + cc) * 128 + h) * 128 + w0 + w_l];
    }
  }
  __syncthreads();
  {
    int c_w = t & 63, w_w = t >> 6;
#pragma unroll
    for (int i = 0; i < 8; ++i) {
      int wl = w_w * 8 + i;
      xt[(((size_t)b * 128 + h) * 128 + w0 + wl) * 64 + c_w] = tile[c_w][wl];
    }
  }
}

// ---------------------------------------------------------------------------
// tap descriptors
// ---------------------------------------------------------------------------
struct TapD { int o00, o01, o10, o11; float w00, w01, w10, w11; };

__device__ __forceinline__ TapD mk_tapd(float oyv, float oxv, int h, int wpix, int kk) {
  TapD t;
  const int dy = kk / 3 - 1, dx = kk - (kk / 3) * 3 - 1;
  float py = oyv + (float)(h + dy);
  float px = oxv + (float)(wpix + dx);
  float y0f = floorf(py), x0f = floorf(px);
  float wy1 = py - y0f, wx1 = px - x0f;
  float wy0 = 1.0f - wy1, wx0 = 1.0f - wx1;
  int y0 = (int)y0f, x0 = (int)x0f, y1 = y0 + 1, x1 = x0 + 1;
  bool vy0 = (unsigned)y0 < (unsigned)HH, vy1 = (unsigned)y1 < (unsigned)HH;
  bool vx0 = (unsigned)x0 < (unsigned)WW, vx1 = (unsigned)x1 < (unsigned)WW;
  t.w00 = (vy0 && vx0) ? wy0 * wx0 : 0.0f;
  t.w01 = (vy0 && vx1) ? wy0 * wx1 : 0.0f;
  t.w10 = (vy1 && vx0) ? wy1 * wx0 : 0.0f;
  t.w11 = (vy1 && vx1) ? wy1 * wx1 : 0.0f;
  int y0c = min(max(y0, 0), HH - 1), y1c = min(max(y1, 0), HH - 1);
  int x0c = min(max(x0, 0), WW - 1), x1c = min(max(x1, 0), WW - 1);
  t.o00 = (y0c * WW + x0c) * CC;
  t.o01 = (y0c * WW + x1c) * CC;
  t.o10 = (y1c * WW + x0c) * CC;
  t.o11 = (y1c * WW + x1c) * CC;
  return t;
}

struct TapO { int ofs; float vf; };

__device__ __forceinline__ TapO mk_tapo(int h, int wpix, int kk) {
  TapO t;
  const int dy = kk / 3 - 1, dx = kk - (kk / 3) * 3 - 1;
  int y = h + dy, x = wpix + dx;
  bool v = ((unsigned)y < (unsigned)HH) && ((unsigned)x < (unsigned)WW);
  t.vf = v ? 1.0f : 0.0f;
  int yc = min(max(y, 0), HH - 1), xc = min(max(x, 0), WW - 1);
  t.ofs = (yc * WW + xc) * CC;
  return t;
}

// ---------------------------------------------------------------------------
// offset conv via MFMA: offs[oc][p] = sum_{ch,k} Wo[oc][ch,k] * patch[ch,k][p].
// Integer taps, zero-pad via vf. One 32x32 M-tile (rows 18..31 zero).
// No LDS, no barriers; full unroll; per-s load-reissue pipeline.
// ---------------------------------------------------------------------------
__global__ __launch_bounds__(256, 2) void offs_mfma(
    const float* __restrict__ xt, const unsigned* __restrict__ wofrag,
    const float* __restrict__ b_off, float* __restrict__ offs) {
  const int swz = (blockIdx.x & 7) * 64 + (blockIdx.x >> 3);
  const int h = swz & 127, b = swz >> 7;
  const int l = threadIdx.x & 63, wv = threadIdx.x >> 6;
  const int P = l & 31, g = l >> 5;
  const int wpix = wv * 32 + P;

  f32x16 acc = {0,0,0,0,0,0,0,0,0,0,0,0,0,0,0,0};
  const float* xb = xt + (size_t)b * HW * CC;

  float4 CR[8];
  TapO tc = mk_tapo(h, wpix, 0);
#pragma unroll
  for (int s = 0; s < 4; ++s) {
    const int cb = s * 16 + g * 8;
    CR[s * 2 + 0] = ld4(xb + tc.ofs + cb);
    CR[s * 2 + 1] = ld4(xb + tc.ofs + cb + 4);
  }

#pragma unroll
  for (int c = 0; c < 9; ++c) {
    TapO tn;
    if (c < 8) tn = mk_tapo(h, wpix, c + 1);
#pragma unroll
    for (int s = 0; s < 4; ++s) {
      const int cb = s * 16 + g * 8;
      float v[8];
#pragma unroll
      for (int j = 0; j < 4; ++j) {
        v[j]     = tc.vf * CR[s * 2 + 0][j];
        v[4 + j] = tc.vf * CR[s * 2 + 1][j];
      }
      short8 sh, sl;
#pragma unroll
      for (int j = 0; j < 8; ++j) {
        unsigned short hb, lb;
        bf16_split(v[j], hb, lb);
        sh[j] = (short)hb;
        sl[j] = (short)lb;
      }
      if (c < 8) {
        CR[s * 2 + 0] = ld4(xb + tn.ofs + cb);
        CR[s * 2 + 1] = ld4(xb + tn.ofs + cb + 4);
      }
      const unsigned* wb = wofrag + ((size_t)((c * 8 + s * 2) * 64 + l)) * 4;
      short8 wh = *(const short8*)(wb);
      short8 wl = *(const short8*)(wb + 256);
      acc = __builtin_amdgcn_mfma_f32_32x32x16_bf16(wh, sh, acc, 0, 0, 0);
      acc = __builtin_amdgcn_mfma_f32_32x32x16_bf16(wh, sl, acc, 0, 0, 0);
      acc = __builtin_amdgcn_mfma_f32_32x32x16_bf16(wl, sh, acc, 0, 0, 0);
    }
    if (c < 8) tc = tn;
  }

#pragma unroll
  for (int r = 0; r < 16; ++r) {
    int oc = (r & 3) + 8 * (r >> 2) + 4 * g;
    if (oc < OCOFF)
      offs[(((size_t)b * OCOFF + oc) * HH + h) * WW + wpix] = acc[r] + b_off[oc];
  }
}

// ---------------------------------------------------------------------------
// deform conv via MFMA. No LDS, no barriers. Full 9-tap unroll with per-s
// load-reissue pipeline: convert CR[s] (tap c) -> reissue CR[s] with tap c+1
// loads -> W loads (global, L1-hot) + 6 MFMAs. ~600cy slack per gather.
// ---------------------------------------------------------------------------
__global__ __launch_bounds__(256, 2) void deform_mfma(
    const float* __restrict__ xt, const float* __restrict__ offs,
    const unsigned* __restrict__ wfrag, const float* __restrict__ bias,
    float* __restrict__ out) {
  const int swz = (blockIdx.x & 7) * 64 + (blockIdx.x >> 3);
  const int h = swz & 127, b = swz >> 7;
  const int l = threadIdx.x & 63, wv = threadIdx.x >> 6;
  const int P = l & 31, g = l >> 5;
  const int wpix = wv * 32 + P;

  f32x16 acc0 = {0,0,0,0,0,0,0,0,0,0,0,0,0,0,0,0};
  f32x16 acc1 = {0,0,0,0,0,0,0,0,0,0,0,0,0,0,0,0};

  const float* xb = xt + (size_t)b * HW * CC;
  const float* ob = offs + (size_t)b * OCOFF * HW + h * WW + wpix;

  float oy[9], ox[9];
#pragma unroll
  for (int k = 0; k < 9; ++k) {
    oy[k] = ob[(size_t)(2 * k) * HW];
    ox[k] = ob[(size_t)(2 * k + 1) * HW];
  }

  float4 CR[32];
  TapD tc = mk_tapd(oy[0], ox[0], h, wpix, 0);
#pragma unroll
  for (int s = 0; s < 4; ++s) {
    const int cb = s * 16 + g * 8;
    CR[s * 8 + 0] = ld4(xb + tc.o00 + cb);  CR[s * 8 + 1] = ld4(xb + tc.o00 + cb + 4);
    CR[s * 8 + 2] = ld4(xb + tc.o01 + cb);  CR[s * 8 + 3] = ld4(xb + tc.o01 + cb + 4);
    CR[s * 8 + 4] = ld4(xb + tc.o10 + cb);  CR[s * 8 + 5] = ld4(xb + tc.o10 + cb + 4);
    CR[s * 8 + 6] = ld4(xb + tc.o11 + cb);  CR[s * 8 + 7] = ld4(xb + tc.o11 + cb + 4);
  }

#pragma unroll
  for (int c = 0; c < 9; ++c) {
    TapD tn;
    if (c < 8) tn = mk_tapd(oy[c + 1], ox[c + 1], h, wpix, c + 1);
#pragma unroll
    for (int s = 0; s < 4; ++s) {
      const int cb = s * 16 + g * 8;
      float v[8];
#pragma unroll
      for (int j = 0; j < 4; ++j) {
        v[j]     = fmaf(tc.w00, CR[s * 8 + 0][j], fmaf(tc.w01, CR[s * 8 + 2][j],
                   fmaf(tc.w10, CR[s * 8 + 4][j], tc.w11 * CR[s * 8 + 6][j])));
        v[4 + j] = fmaf(tc.w00, CR[s * 8 + 1][j], fmaf(tc.w01, CR[s * 8 + 3][j],
                   fmaf(tc.w10, CR[s * 8 + 5][j], tc.w11 * CR[s * 8 + 7][j])));
      }
      short8 sh, sl;
#pragma unroll
      for (int j = 0; j < 8; ++j) {
        unsigned short hb, lb;
        bf16_split(v[j], hb, lb);
        sh[j] = (short)hb;
        sl[j] = (short)lb;
      }
      if (c < 8) {
        CR[s * 8 + 0] = ld4(xb + tn.o00 + cb);  CR[s * 8 + 1] = ld4(xb + tn.o00 + cb + 4);
        CR[s * 8 + 2] = ld4(xb + tn.o01 + cb);  CR[s * 8 + 3] = ld4(xb + tn.o01 + cb + 4);
        CR[s * 8 + 4] = ld4(xb + tn.o10 + cb);  CR[s * 8 + 5] = ld4(xb + tn.o10 + cb + 4);
        CR[s * 8 + 6] = ld4(xb + tn.o11 + cb);  CR[s * 8 + 7] = ld4(xb + tn.o11 + cb + 4);
      }
      const unsigned* wb = wfrag + ((size_t)((c * 16 + s * 2) * 64 + l)) * 4;
      short8 wh0 = *(const short8*)(wb);            // m=0, hh=0
      short8 wl0 = *(const short8*)(wb + 256);      // m=0, hh=1
      short8 wh1 = *(const short8*)(wb + 2048);     // m=1, hh=0
      short8 wl1 = *(const short8*)(wb + 2304);     // m=1, hh=1
      acc0 = __builtin_amdgcn_mfma_f32_32x32x16_bf16(wh0, sh, acc0, 0, 0, 0);
      acc0 = __builtin_amdgcn_mfma_f32_32x32x16_bf16(wh0, sl, acc0, 0, 0, 0);
      acc0 = __builtin_amdgcn_mfma_f32_32x32x16_bf16(wl0, sh, acc0, 0, 0, 0);
      acc1 = __builtin_amdgcn_mfma_f32_32x32x16_bf16(wh1, sh, acc1, 0, 0, 0);
      acc1 = __builtin_amdgcn_mfma_f32_32x32x16_bf16(wh1, sl, acc1, 0, 0, 0);
      acc1 = __builtin_amdgcn_mfma_f32_32x32x16_bf16(wl1, sh, acc1, 0, 0, 0);
    }
    if (c < 8) tc = tn;
  }

  // epilogue: bias + store. D layout (32x32): col=lane&31, row=(r&3)+8*(r>>2)+4*g.
#pragma unroll
  for (int r = 0; r < 16; ++r) {
    int o0 = (r & 3) + 8 * (r >> 2) + 4 * g;
    out[(((size_t)b * 64 + o0) * 128 + h) * 128 + wpix] = acc0[r] + bias[o0];
    int o1 = 32 + o0;
    out[(((size_t)b * 64 + o1) * 128 + h) * 128 + wpix] = acc1[r] + bias[o1];
  }
}

// ---------------------------------------------------------------------------
extern "C" void kernel_launch(void* const* d_in, const int* in_sizes, int n_in,
                              void* d_out, int out_size, void* d_ws, size_t ws_size,
                              hipStream_t stream) {
  const float* x      = (const float*)d_in[0];
  const float* w_off  = (const float*)d_in[1];
  const float* b_off  = (const float*)d_in[2];
  const float* weight = (const float*)d_in[3];
  const float* bias   = (const float*)d_in[4];
  float* out = (float*)d_out;

  // workspace: xt | offs | wfrag | wofrag  (~21.7 MB)
  float*    xt     = (float*)d_ws;                 // 4*128*128*64 = 4,194,304 f
  float*    offs   = xt + (size_t)4194304;         // 4*18*16384   = 1,179,648 f
  unsigned* wfrag  = (unsigned*)(offs + 1179648);  // 36,864 dw
  unsigned* wofrag = wfrag + 36864;                // 18,432 dw

  prep_wfrag<<<144, 256, 0, stream>>>(weight, wfrag);
  prep_wofrag<<<72, 256, 0, stream>>>(w_off, wofrag);
  transpose_x<<<2048, 256, 0, stream>>>(x, xt);

  offs_mfma<<<512, 256, 0, stream>>>(xt, wofrag, b_off, offs);
  deform_mfma<<<512, 256, 0, stream>>>(xt, offs, wfrag, bias, out);
}

// Round 6
// 180.016 us; speedup vs baseline: 1.1915x; 1.0006x over previous
//
#include <hip/hip_runtime.h>
#include <hip/hip_bf16.h>

// Problem constants: B=4, C=64, O=64, H=W=128, K=3, PAD=1
#define BB 4
#define CC 64
#define OO 64
#define HH 128
#define WW 128
#define HW (HH * WW)       // 16384
#define K2 9
#define OCOFF 18           // 2*K2 offset channels

typedef __attribute__((ext_vector_type(8))) short short8;     // 8 bf16 = 4 VGPR
typedef __attribute__((ext_vector_type(16))) float f32x16;    // MFMA 32x32 acc

// RNE float->bf16 (bits), plus residual ("lo") term. Finite inputs only.
__device__ __forceinline__ unsigned short bf16_rne(float v) {
  unsigned u = __builtin_bit_cast(unsigned, v);
  return (unsigned short)((u + 0x7FFFu + ((u >> 16) & 1u)) >> 16);
}
__device__ __forceinline__ void bf16_split(float v, unsigned short& hi, unsigned short& lo) {
  hi = bf16_rne(v);
  float hf = __builtin_bit_cast(float, (unsigned)hi << 16);
  lo = bf16_rne(v - hf);
}
__device__ __forceinline__ float4 ld4(const float* p) { return *(const float4*)p; }

// ---------------------------------------------------------------------------
// prep: main weights -> MFMA A-fragment-linear hi/lo bf16. (validated r4/r5)
// dword d = ((c*16 + m*8 + s*2 + hh)*64 + l)*4 + j2
// value: A[o = m*32 + (l&31)][ch = s*16 + (l>>5)*8 + j] = weight[o][ch][c]
// ---------------------------------------------------------------------------
__global__ __launch_bounds__(256) void prep_wfrag(
    const float* __restrict__ weight, unsigned* __restrict__ wf) {
  int d = blockIdx.x * 256 + threadIdx.x;
  if (d >= 9 * 4096) return;
  int j2 = d & 3, l = (d >> 2) & 63, hh = (d >> 8) & 1, s = (d >> 9) & 3,
      m = (d >> 11) & 1, c = d >> 12;
  int o = m * 32 + (l & 31);
  int g = l >> 5;
  int ch0 = s * 16 + g * 8 + j2 * 2;
  float v0 = weight[(o * 64 + ch0) * 9 + c];
  float v1 = weight[(o * 64 + ch0 + 1) * 9 + c];
  unsigned short h0, l0, h1, l1;
  bf16_split(v0, h0, l0);
  bf16_split(v1, h1, l1);
  unsigned short b0 = hh ? l0 : h0;
  unsigned short b1 = hh ? l1 : h1;
  wf[d] = (unsigned)b0 | ((unsigned)b1 << 16);
}

// ---------------------------------------------------------------------------
// prep: offset-conv weights -> A-fragments (rows 0..17 = oc, 18..31 zero).
// dword d = ((c*8 + s*2 + hh)*64 + l)*4 + j2    (validated r5)
// ---------------------------------------------------------------------------
__global__ __launch_bounds__(256) void prep_wofrag(
    const float* __restrict__ w_off, unsigned* __restrict__ wof) {
  int d = blockIdx.x * 256 + threadIdx.x;
  if (d >= 9 * 2048) return;
  int j2 = d & 3, l = (d >> 2) & 63, hh = (d >> 8) & 1, s = (d >> 9) & 3,
      c = d >> 11;
  int oc = l & 31;
  int g = l >> 5;
  int ch0 = s * 16 + g * 8 + j2 * 2;
  unsigned r = 0;
  if (oc < OCOFF) {
    float v0 = w_off[(oc * 64 + ch0) * 9 + c];
    float v1 = w_off[(oc * 64 + ch0 + 1) * 9 + c];
    unsigned short h0, l0, h1, l1;
    bf16_split(v0, h0, l0);
    bf16_split(v1, h1, l1);
    unsigned short b0 = hh ? l0 : h0;
    unsigned short b1 = hh ? l1 : h1;
    r = (unsigned)b0 | ((unsigned)b1 << 16);
  }
  wof[d] = r;
}

// ---------------------------------------------------------------------------
// NCHW -> NHWC transpose: x_t[b][h][w][c]   (validated r4/r5)
// ---------------------------------------------------------------------------
__global__ __launch_bounds__(256) void transpose_x(
    const float* __restrict__ x, float* __restrict__ xt) {
  __shared__ float tile[64][33];
  int blk = blockIdx.x;
  int wt = blk & 3, h = (blk >> 2) & 127, b = blk >> 9;
  int w0 = wt * 32;
  int t = threadIdx.x;
  {
    int w_l = t & 31, c_l = t >> 5;
#pragma unroll
    for (int i = 0; i < 8; ++i) {
      int cc = c_l * 8 + i;
      tile[cc][w_l] = x[(((size_t)b * 64 + cc) * 128 + h) * 128 + w0 + w_l];
    }
  }
  __syncthreads();
  {
    int c_w = t & 63, w_w = t >> 6;
#pragma unroll
    for (int i = 0; i < 8; ++i) {
      int wl = w_w * 8 + i;
      xt[(((size_t)b * 128 + h) * 128 + w0 + wl) * 64 + c_w] = tile[c_w][wl];
    }
  }
}

// ---------------------------------------------------------------------------
// tap descriptors
// ---------------------------------------------------------------------------
struct TapD { int o00, o01, o10, o11; float w00, w01, w10, w11; };

__device__ __forceinline__ TapD mk_tapd(float oyv, float oxv, int h, int wpix, int kk) {
  TapD t;
  const int dy = kk / 3 - 1, dx = kk - (kk / 3) * 3 - 1;
  float py = oyv + (float)(h + dy);
  float px = oxv + (float)(wpix + dx);
  float y0f = floorf(py), x0f = floorf(px);
  float wy1 = py - y0f, wx1 = px - x0f;
  float wy0 = 1.0f - wy1, wx0 = 1.0f - wx1;
  int y0 = (int)y0f, x0 = (int)x0f, y1 = y0 + 1, x1 = x0 + 1;
  bool vy0 = (unsigned)y0 < (unsigned)HH, vy1 = (unsigned)y1 < (unsigned)HH;
  bool vx0 = (unsigned)x0 < (unsigned)WW, vx1 = (unsigned)x1 < (unsigned)WW;
  t.w00 = (vy0 && vx0) ? wy0 * wx0 : 0.0f;
  t.w01 = (vy0 && vx1) ? wy0 * wx1 : 0.0f;
  t.w10 = (vy1 && vx0) ? wy1 * wx0 : 0.0f;
  t.w11 = (vy1 && vx1) ? wy1 * wx1 : 0.0f;
  int y0c = min(max(y0, 0), HH - 1), y1c = min(max(y1, 0), HH - 1);
  int x0c = min(max(x0, 0), WW - 1), x1c = min(max(x1, 0), WW - 1);
  t.o00 = (y0c * WW + x0c) * CC;
  t.o01 = (y0c * WW + x1c) * CC;
  t.o10 = (y1c * WW + x0c) * CC;
  t.o11 = (y1c * WW + x1c) * CC;
  return t;
}

struct TapO { int ofs; float vf; };

__device__ __forceinline__ TapO mk_tapo(int h, int wpix, int kk) {
  TapO t;
  const int dy = kk / 3 - 1, dx = kk - (kk / 3) * 3 - 1;
  int y = h + dy, x = wpix + dx;
  bool v = ((unsigned)y < (unsigned)HH) && ((unsigned)x < (unsigned)WW);
  t.vf = v ? 1.0f : 0.0f;
  int yc = min(max(y, 0), HH - 1), xc = min(max(x, 0), WW - 1);
  t.ofs = (yc * WW + xc) * CC;
  return t;
}

// ---------------------------------------------------------------------------
// deform conv via MFMA, K-SPLIT for occupancy.
// Block = 256 thr = 4 waves = 2 px-groups (64 px) x 2 kstep-halves.
// Wave (pg, sh): 32 px x 64 o, ksteps s in {2sh, 2sh+1} of every tap.
// Partial accs reduced via skewed LDS (lane-stride 33 => conflict-free).
// Grid = 1024 blocks (b, h, half-row) -> 16 waves/CU at VGPR<=128.
// ---------------------------------------------------------------------------
__global__ __launch_bounds__(256, 4) void deform_mfma(
    const float* __restrict__ xt, const float* __restrict__ offs,
    const unsigned* __restrict__ wfrag, const float* __restrict__ bias,
    float* __restrict__ out) {
  __shared__ float lred[2 * 64 * 33];   // 16.5 KB

  const int blk = blockIdx.x;
  const int sx = (blk & 7) * 128 + (blk >> 3);       // bijective (1024 % 8 == 0)
  const int half = sx & 1, h = (sx >> 1) & 127, b = sx >> 8;
  const int tid = threadIdx.x;
  const int l = tid & 63, wv = tid >> 6;
  const int pg = wv & 1, sh = wv >> 1;
  const int P = l & 31, g = l >> 5;
  const int wpix = half * 64 + pg * 32 + P;
  const int s0 = sh * 2;

  f32x16 acc0 = {0,0,0,0,0,0,0,0,0,0,0,0,0,0,0,0};
  f32x16 acc1 = {0,0,0,0,0,0,0,0,0,0,0,0,0,0,0,0};

  const float* xb = xt + (size_t)b * HW * CC;
  const float* ob = offs + (size_t)b * OCOFF * HW + h * WW + wpix;

  float oyc = ob[0];
  float oxc = ob[HW];

#pragma unroll
  for (int c = 0; c < 9; ++c) {
    float oyn = 0.0f, oxn = 0.0f;
    if (c < 8) {                       // prefetch next tap's offsets
      oyn = ob[(size_t)(2 * c + 2) * HW];
      oxn = ob[(size_t)(2 * c + 3) * HW];
    }
    TapD t = mk_tapd(oyc, oxc, h, wpix, c);
#pragma unroll
    for (int si = 0; si < 2; ++si) {
      const int s = s0 + si;
      const int cb = s * 16 + g * 8;
      float4 r00 = ld4(xb + t.o00 + cb), r01 = ld4(xb + t.o00 + cb + 4);
      float4 r10 = ld4(xb + t.o01 + cb), r11 = ld4(xb + t.o01 + cb + 4);
      float4 r20 = ld4(xb + t.o10 + cb), r21 = ld4(xb + t.o10 + cb + 4);
      float4 r30 = ld4(xb + t.o11 + cb), r31 = ld4(xb + t.o11 + cb + 4);
      float v[8];
#pragma unroll
      for (int j = 0; j < 4; ++j) {
        v[j]     = fmaf(t.w00, r00[j], fmaf(t.w01, r10[j],
                   fmaf(t.w10, r20[j], t.w11 * r30[j])));
        v[4 + j] = fmaf(t.w00, r01[j], fmaf(t.w01, r11[j],
                   fmaf(t.w10, r21[j], t.w11 * r31[j])));
      }
      short8 sh8, sl8;
#pragma unroll
      for (int j = 0; j < 8; ++j) {
        unsigned short hb, lb;
        bf16_split(v[j], hb, lb);
        sh8[j] = (short)hb;
        sl8[j] = (short)lb;
      }
      const unsigned* wb = wfrag + ((size_t)((c * 16 + s * 2) * 64 + l)) * 4;
      short8 wh0 = *(const short8*)(wb);            // m=0, hi
      short8 wl0 = *(const short8*)(wb + 256);      // m=0, lo
      short8 wh1 = *(const short8*)(wb + 2048);     // m=1, hi
      short8 wl1 = *(const short8*)(wb + 2304);     // m=1, lo
      acc0 = __builtin_amdgcn_mfma_f32_32x32x16_bf16(wh0, sh8, acc0, 0, 0, 0);
      acc0 = __builtin_amdgcn_mfma_f32_32x32x16_bf16(wh0, sl8, acc0, 0, 0, 0);
      acc0 = __builtin_amdgcn_mfma_f32_32x32x16_bf16(wl0, sh8, acc0, 0, 0, 0);
      acc1 = __builtin_amdgcn_mfma_f32_32x32x16_bf16(wh1, sh8, acc1, 0, 0, 0);
      acc1 = __builtin_amdgcn_mfma_f32_32x32x16_bf16(wh1, sl8, acc1, 0, 0, 0);
      acc1 = __builtin_amdgcn_mfma_f32_32x32x16_bf16(wl1, sh8, acc1, 0, 0, 0);
    }
    if (c < 8) { oyc = oyn; oxc = oxn; }
  }

  // K-reduction: sh==1 waves park partials in LDS (skew 33 -> conflict-free)
  const int base = pg * (64 * 33) + l * 33;
  if (sh == 1) {
#pragma unroll
    for (int r = 0; r < 16; ++r) {
      lred[base + r]      = acc0[r];
      lred[base + 16 + r] = acc1[r];
    }
  }
  __syncthreads();
  if (sh == 0) {
#pragma unroll
    for (int r = 0; r < 16; ++r) {
      float a0 = acc0[r] + lred[base + r];
      float a1 = acc1[r] + lred[base + 16 + r];
      int o0 = (r & 3) + 8 * (r >> 2) + 4 * g;
      out[(((size_t)b * 64 + o0) * 128 + h) * 128 + wpix]      = a0 + bias[o0];
      out[(((size_t)b * 64 + 32 + o0) * 128 + h) * 128 + wpix] = a1 + bias[32 + o0];
    }
  }
}

// ---------------------------------------------------------------------------
// offset conv via MFMA, same K-split block structure. Integer taps.
// ---------------------------------------------------------------------------
__global__ __launch_bounds__(256, 4) void offs_mfma(
    const float* __restrict__ xt, const unsigned* __restrict__ wofrag,
    const float* __restrict__ b_off, float* __restrict__ offs) {
  __shared__ float lred[2 * 64 * 17];   // 8.5 KB

  const int blk = blockIdx.x;
  const int sx = (blk & 7) * 128 + (blk >> 3);
  const int half = sx & 1, h = (sx >> 1) & 127, b = sx >> 8;
  const int tid = threadIdx.x;
  const int l = tid & 63, wv = tid >> 6;
  const int pg = wv & 1, sh = wv >> 1;
  const int P = l & 31, g = l >> 5;
  const int wpix = half * 64 + pg * 32 + P;
  const int s0 = sh * 2;

  f32x16 acc = {0,0,0,0,0,0,0,0,0,0,0,0,0,0,0,0};
  const float* xb = xt + (size_t)b * HW * CC;

#pragma unroll
  for (int c = 0; c < 9; ++c) {
    TapO t = mk_tapo(h, wpix, c);
#pragma unroll
    for (int si = 0; si < 2; ++si) {
      const int s = s0 + si;
      const int cb = s * 16 + g * 8;
      float4 r0 = ld4(xb + t.ofs + cb), r1 = ld4(xb + t.ofs + cb + 4);
      float v[8];
#pragma unroll
      for (int j = 0; j < 4; ++j) {
        v[j]     = t.vf * r0[j];
        v[4 + j] = t.vf * r1[j];
      }
      short8 sh8, sl8;
#pragma unroll
      for (int j = 0; j < 8; ++j) {
        unsigned short hb, lb;
        bf16_split(v[j], hb, lb);
        sh8[j] = (short)hb;
        sl8[j] = (short)lb;
      }
      const unsigned* wb = wofrag + ((size_t)((c * 8 + s * 2) * 64 + l)) * 4;
      short8 wh = *(const short8*)(wb);
      short8 wl = *(const short8*)(wb + 256);
      acc = __builtin_amdgcn_mfma_f32_32x32x16_bf16(wh, sh8, acc, 0, 0, 0);
      acc = __builtin_amdgcn_mfma_f32_32x32x16_bf16(wh, sl8, acc, 0, 0, 0);
      acc = __builtin_amdgcn_mfma_f32_32x32x16_bf16(wl, sh8, acc, 0, 0, 0);
    }
  }

  const int base = pg * (64 * 17) + l * 17;
  if (sh == 1) {
#pragma unroll
    for (int r = 0; r < 16; ++r) lred[base + r] = acc[r];
  }
  __syncthreads();
  if (sh == 0) {
#pragma unroll
    for (int r = 0; r < 16; ++r) {
      int oc = (r & 3) + 8 * (r >> 2) + 4 * g;
      if (oc < OCOFF) {
        float a = acc[r] + lred[base + r];
        offs[(((size_t)b * OCOFF + oc) * HH + h) * WW + wpix] = a + b_off[oc];
      }
    }
  }
}

// ---------------------------------------------------------------------------
extern "C" void kernel_launch(void* const* d_in, const int* in_sizes, int n_in,
                              void* d_out, int out_size, void* d_ws, size_t ws_size,
                              hipStream_t stream) {
  const float* x      = (const float*)d_in[0];
  const float* w_off  = (const float*)d_in[1];
  const float* b_off  = (const float*)d_in[2];
  const float* weight = (const float*)d_in[3];
  const float* bias   = (const float*)d_in[4];
  float* out = (float*)d_out;

  // workspace: xt | offs | wfrag | wofrag  (~21.7 MB)
  float*    xt     = (float*)d_ws;                 // 4*128*128*64 = 4,194,304 f
  float*    offs   = xt + (size_t)4194304;         // 4*18*16384   = 1,179,648 f
  unsigned* wfrag  = (unsigned*)(offs + 1179648);  // 36,864 dw
  unsigned* wofrag = wfrag + 36864;                // 18,432 dw

  prep_wfrag<<<144, 256, 0, stream>>>(weight, wfrag);
  prep_wofrag<<<72, 256, 0, stream>>>(w_off, wofrag);
  transpose_x<<<2048, 256, 0, stream>>>(x, xt);

  offs_mfma<<<1024, 256, 0, stream>>>(xt, wofrag, b_off, offs);
  deform_mfma<<<1024, 256, 0, stream>>>(xt, offs, wfrag, bias, out);
}

// Round 7
// 150.283 us; speedup vs baseline: 1.4272x; 1.1978x over previous
//
#include <hip/hip_runtime.h>
#include <hip/hip_bf16.h>

// Problem constants: B=4, C=64, O=64, H=W=128, K=3, PAD=1
#define BB 4
#define CC 64
#define OO 64
#define HH 128
#define WW 128
#define HW (HH * WW)       // 16384
#define K2 9
#define OCOFF 18           // 2*K2 offset channels
#define SMP_STRIDE 36      // u32 per px row in LDS (32 data + 4 pad)

typedef __attribute__((ext_vector_type(8))) short short8;     // 8 bf16 = 4 VGPR
typedef __attribute__((ext_vector_type(16))) float f32x16;    // MFMA 32x32 acc

// RNE float->bf16 (bits), plus residual ("lo") term. Finite inputs only.
__device__ __forceinline__ unsigned short bf16_rne(float v) {
  unsigned u = __builtin_bit_cast(unsigned, v);
  return (unsigned short)((u + 0x7FFFu + ((u >> 16) & 1u)) >> 16);
}
__device__ __forceinline__ void bf16_split(float v, unsigned short& hi, unsigned short& lo) {
  hi = bf16_rne(v);
  float hf = __builtin_bit_cast(float, (unsigned)hi << 16);
  lo = bf16_rne(v - hf);
}
__device__ __forceinline__ float4 ld4(const float* p) { return *(const float4*)p; }

// ---------------------------------------------------------------------------
// prep: main weights -> MFMA A-fragment-linear hi/lo bf16. (validated r4-r6)
// dword d = ((c*16 + m*8 + s*2 + hh)*64 + l)*4 + j2
// value: A[o = m*32 + (l&31)][ch = s*16 + (l>>5)*8 + j] = weight[o][ch][c]
// ---------------------------------------------------------------------------
__global__ __launch_bounds__(256) void prep_wfrag(
    const float* __restrict__ weight, unsigned* __restrict__ wf) {
  int d = blockIdx.x * 256 + threadIdx.x;
  if (d >= 9 * 4096) return;
  int j2 = d & 3, l = (d >> 2) & 63, hh = (d >> 8) & 1, s = (d >> 9) & 3,
      m = (d >> 11) & 1, c = d >> 12;
  int o = m * 32 + (l & 31);
  int g = l >> 5;
  int ch0 = s * 16 + g * 8 + j2 * 2;
  float v0 = weight[(o * 64 + ch0) * 9 + c];
  float v1 = weight[(o * 64 + ch0 + 1) * 9 + c];
  unsigned short h0, l0, h1, l1;
  bf16_split(v0, h0, l0);
  bf16_split(v1, h1, l1);
  unsigned short b0 = hh ? l0 : h0;
  unsigned short b1 = hh ? l1 : h1;
  wf[d] = (unsigned)b0 | ((unsigned)b1 << 16);
}

// ---------------------------------------------------------------------------
// prep: offset-conv weights -> A-fragments (rows 0..17 = oc, 18..31 zero).
// dword d = ((c*8 + s*2 + hh)*64 + l)*4 + j2    (validated r5/r6)
// ---------------------------------------------------------------------------
__global__ __launch_bounds__(256) void prep_wofrag(
    const float* __restrict__ w_off, unsigned* __restrict__ wof) {
  int d = blockIdx.x * 256 + threadIdx.x;
  if (d >= 9 * 2048) return;
  int j2 = d & 3, l = (d >> 2) & 63, hh = (d >> 8) & 1, s = (d >> 9) & 3,
      c = d >> 11;
  int oc = l & 31;
  int g = l >> 5;
  int ch0 = s * 16 + g * 8 + j2 * 2;
  unsigned r = 0;
  if (oc < OCOFF) {
    float v0 = w_off[(oc * 64 + ch0) * 9 + c];
    float v1 = w_off[(oc * 64 + ch0 + 1) * 9 + c];
    unsigned short h0, l0, h1, l1;
    bf16_split(v0, h0, l0);
    bf16_split(v1, h1, l1);
    unsigned short b0 = hh ? l0 : h0;
    unsigned short b1 = hh ? l1 : h1;
    r = (unsigned)b0 | ((unsigned)b1 << 16);
  }
  wof[d] = r;
}

// ---------------------------------------------------------------------------
// NCHW -> NHWC transpose: x_t[b][h][w][c]   (validated r4-r6)
// ---------------------------------------------------------------------------
__global__ __launch_bounds__(256) void transpose_x(
    const float* __restrict__ x, float* __restrict__ xt) {
  __shared__ float tile[64][33];
  int blk = blockIdx.x;
  int wt = blk & 3, h = (blk >> 2) & 127, b = blk >> 9;
  int w0 = wt * 32;
  int t = threadIdx.x;
  {
    int w_l = t & 31, c_l = t >> 5;
#pragma unroll
    for (int i = 0; i < 8; ++i) {
      int cc = c_l * 8 + i;
      tile[cc][w_l] = x[(((size_t)b * 64 + cc) * 128 + h) * 128 + w0 + w_l];
    }
  }
  __syncthreads();
  {
    int c_w = t & 63, w_w = t >> 6;
#pragma unroll
    for (int i = 0; i < 8; ++i) {
      int wl = w_w * 8 + i;
      xt[(((size_t)b * 128 + h) * 128 + w0 + wl) * 64 + c_w] = tile[c_w][wl];
    }
  }
}

// ---------------------------------------------------------------------------
// tap descriptors (validated r4-r6)
// ---------------------------------------------------------------------------
struct TapD { int o00, o01, o10, o11; float w00, w01, w10, w11; };

__device__ __forceinline__ TapD mk_tapd(float oyv, float oxv, int h, int wpix, int kk) {
  TapD t;
  const int dy = kk / 3 - 1, dx = kk - (kk / 3) * 3 - 1;
  float py = oyv + (float)(h + dy);
  float px = oxv + (float)(wpix + dx);
  float y0f = floorf(py), x0f = floorf(px);
  float wy1 = py - y0f, wx1 = px - x0f;
  float wy0 = 1.0f - wy1, wx0 = 1.0f - wx1;
  int y0 = (int)y0f, x0 = (int)x0f, y1 = y0 + 1, x1 = x0 + 1;
  bool vy0 = (unsigned)y0 < (unsigned)HH, vy1 = (unsigned)y1 < (unsigned)HH;
  bool vx0 = (unsigned)x0 < (unsigned)WW, vx1 = (unsigned)x1 < (unsigned)WW;
  t.w00 = (vy0 && vx0) ? wy0 * wx0 : 0.0f;
  t.w01 = (vy0 && vx1) ? wy0 * wx1 : 0.0f;
  t.w10 = (vy1 && vx0) ? wy1 * wx0 : 0.0f;
  t.w11 = (vy1 && vx1) ? wy1 * wx1 : 0.0f;
  int y0c = min(max(y0, 0), HH - 1), y1c = min(max(y1, 0), HH - 1);
  int x0c = min(max(x0, 0), WW - 1), x1c = min(max(x1, 0), WW - 1);
  t.o00 = (y0c * WW + x0c) * CC;
  t.o01 = (y0c * WW + x1c) * CC;
  t.o10 = (y1c * WW + x0c) * CC;
  t.o11 = (y1c * WW + x1c) * CC;
  return t;
}

struct TapO { int ofs; float vf; };

__device__ __forceinline__ TapO mk_tapo(int h, int wpix, int kk) {
  TapO t;
  const int dy = kk / 3 - 1, dx = kk - (kk / 3) * 3 - 1;
  int y = h + dy, x = wpix + dx;
  bool v = ((unsigned)y < (unsigned)HH) && ((unsigned)x < (unsigned)WW);
  t.vf = v ? 1.0f : 0.0f;
  int yc = min(max(y, 0), HH - 1), xc = min(max(x, 0), WW - 1);
  t.ofs = (yc * WW + xc) * CC;
  return t;
}

// ---------------------------------------------------------------------------
// gather-transpose helpers. Lane map inside a wave: j = l&7 (ch granule),
// pq = l>>3 (px within octet). Round r covers px pl = r*8+pq (wave-local).
// Each ld4 reads 8 FULL 128B lines (one per px), touched exactly once.
// ---------------------------------------------------------------------------
__device__ __forceinline__ void issueD(float4 (&st)[8], const float* xb,
                                       const TapD& t, int j4) {
  st[0] = ld4(xb + t.o00 + j4);      st[1] = ld4(xb + t.o01 + j4);
  st[2] = ld4(xb + t.o10 + j4);      st[3] = ld4(xb + t.o11 + j4);
  st[4] = ld4(xb + t.o00 + 32 + j4); st[5] = ld4(xb + t.o01 + 32 + j4);
  st[6] = ld4(xb + t.o10 + 32 + j4); st[7] = ld4(xb + t.o11 + 32 + j4);
}
__device__ __forceinline__ void issueO(float4 (&st)[2], const float* xb,
                                       const TapO& t, int j4) {
  st[0] = ld4(xb + t.ofs + j4);
  st[1] = ld4(xb + t.ofs + 32 + j4);
}

__device__ __forceinline__ void pack_write(unsigned* mh, unsigned* ml,
                                           int pl, int j, int hf,
                                           const float v[4]) {
  unsigned short h0, l0, h1, l1, h2, l2, h3, l3;
  bf16_split(v[0], h0, l0); bf16_split(v[1], h1, l1);
  bf16_split(v[2], h2, l2); bf16_split(v[3], h3, l3);
  int idx = pl * SMP_STRIDE + hf * 16 + j * 2;
  *(uint2*)&mh[idx] = make_uint2((unsigned)h0 | ((unsigned)h1 << 16),
                                 (unsigned)h2 | ((unsigned)h3 << 16));
  *(uint2*)&ml[idx] = make_uint2((unsigned)l0 | ((unsigned)l1 << 16),
                                 (unsigned)l2 | ((unsigned)l3 << 16));
}

__device__ __forceinline__ void consumeD(unsigned* mh, unsigned* ml,
                                         int pl, int j,
                                         const float4 (&st)[8], const TapD& t) {
#pragma unroll
  for (int hf = 0; hf < 2; ++hf) {
    float v[4];
#pragma unroll
    for (int q = 0; q < 4; ++q)
      v[q] = fmaf(t.w00, st[hf * 4 + 0][q], fmaf(t.w01, st[hf * 4 + 1][q],
             fmaf(t.w10, st[hf * 4 + 2][q], t.w11 * st[hf * 4 + 3][q])));
    pack_write(mh, ml, pl, j, hf, v);
  }
}

__device__ __forceinline__ void consumeO(unsigned* mh, unsigned* ml,
                                         int pl, int j,
                                         const float4 (&st)[2], const TapO& t) {
#pragma unroll
  for (int hf = 0; hf < 2; ++hf) {
    float v[4];
#pragma unroll
    for (int q = 0; q < 4; ++q) v[q] = t.vf * st[hf][q];
    pack_write(mh, ml, pl, j, hf, v);
  }
}

// ---------------------------------------------------------------------------
// fused kernel: phase 1 computes the 18 offset channels for the block's own
// 64 px (into LDS), phase 2 does the deformable sampling + main einsum.
// Block = 128 thr = 2 independent waves (no barriers). Wave = 32 px, full K.
// Grid = 1024 (b x h x 2 segments), XCD-bijective swizzle.
// ---------------------------------------------------------------------------
__global__ __launch_bounds__(128, 2) void fused_deform(
    const float* __restrict__ xt, const unsigned* __restrict__ wfrag,
    const unsigned* __restrict__ wofrag, const float* __restrict__ b_off,
    const float* __restrict__ bias, float* __restrict__ out) {
  __shared__ __align__(16) unsigned smph[2][32 * SMP_STRIDE];
  __shared__ __align__(16) unsigned smpl[2][32 * SMP_STRIDE];
  __shared__ __align__(16) float offs_lds[2][32 * OCOFF];

  const int blk = blockIdx.x;
  const int sx = (blk & 7) * 128 + (blk >> 3);   // bijective: 1024 % 8 == 0
  const int seg = sx & 1, h = (sx >> 1) & 127, b = sx >> 8;
  const int tid = threadIdx.x;
  const int l = tid & 63, wv = tid >> 6;
  const int P = l & 31, g = l >> 5;
  const int j = l & 7, pq = l >> 3;
  const int j4 = j * 4;
  const int wbase = seg * 64 + wv * 32;          // w coord of wave's px 0

  const float* xb = xt + (size_t)b * HW * CC;
  unsigned* mh = smph[wv];
  unsigned* ml = smpl[wv];
  float* ol = offs_lds[wv];

  // ======================= PHASE 1: offset conv =======================
  {
    f32x16 accO = {0,0,0,0,0,0,0,0,0,0,0,0,0,0,0,0};
    TapO tA, tB;
    float4 sA[2], sB[2];
    tA = mk_tapo(h, wbase + pq, 0);
    issueO(sA, xb, tA, j4);
#pragma unroll
    for (int c = 0; c < 9; ++c) {
      tB = mk_tapo(h, wbase + 8 + pq, c);
      issueO(sB, xb, tB, j4);
      consumeO(mh, ml, pq, j, sA, tA);
      tA = mk_tapo(h, wbase + 16 + pq, c);
      issueO(sA, xb, tA, j4);
      consumeO(mh, ml, 8 + pq, j, sB, tB);
      tB = mk_tapo(h, wbase + 24 + pq, c);
      issueO(sB, xb, tB, j4);
      consumeO(mh, ml, 16 + pq, j, sA, tA);
      if (c < 8) {
        tA = mk_tapo(h, wbase + pq, c + 1);
        issueO(sA, xb, tA, j4);
      }
      consumeO(mh, ml, 24 + pq, j, sB, tB);
      // phase B: B-frags from LDS, 3 MFMA per kstep
#pragma unroll
      for (int s = 0; s < 4; ++s) {
        int ridx = P * SMP_STRIDE + s * 8 + g * 4;
        short8 sh8 = *(const short8*)&mh[ridx];
        short8 sl8 = *(const short8*)&ml[ridx];
        const unsigned* wb = wofrag + ((size_t)((c * 8 + s * 2) * 64 + l)) * 4;
        short8 wh = *(const short8*)(wb);
        short8 wl = *(const short8*)(wb + 256);
        accO = __builtin_amdgcn_mfma_f32_32x32x16_bf16(wh, sh8, accO, 0, 0, 0);
        accO = __builtin_amdgcn_mfma_f32_32x32x16_bf16(wh, sl8, accO, 0, 0, 0);
        accO = __builtin_amdgcn_mfma_f32_32x32x16_bf16(wl, sh8, accO, 0, 0, 0);
      }
    }
    // park offsets in LDS: D layout col=P, row=(r&3)+8*(r>>2)+4g (validated)
#pragma unroll
    for (int r = 0; r < 16; ++r) {
      int oc = (r & 3) + 8 * (r >> 2) + 4 * g;
      if (oc < OCOFF) ol[P * OCOFF + oc] = accO[r] + b_off[oc];
    }
  }

  // ======================= PHASE 2: deformable conv ====================
  f32x16 acc0 = {0,0,0,0,0,0,0,0,0,0,0,0,0,0,0,0};
  f32x16 acc1 = {0,0,0,0,0,0,0,0,0,0,0,0,0,0,0,0};
  {
    TapD tA, tB;
    float4 sA[8], sB[8];
    {
      float2 o = *(const float2*)&ol[pq * OCOFF + 0];
      tA = mk_tapd(o.x, o.y, h, wbase + pq, 0);
      issueD(sA, xb, tA, j4);
    }
#pragma unroll
    for (int c = 0; c < 9; ++c) {
      {
        float2 o = *(const float2*)&ol[(8 + pq) * OCOFF + 2 * c];
        tB = mk_tapd(o.x, o.y, h, wbase + 8 + pq, c);
        issueD(sB, xb, tB, j4);
      }
      consumeD(mh, ml, pq, j, sA, tA);
      {
        float2 o = *(const float2*)&ol[(16 + pq) * OCOFF + 2 * c];
        tA = mk_tapd(o.x, o.y, h, wbase + 16 + pq, c);
        issueD(sA, xb, tA, j4);
      }
      consumeD(mh, ml, 8 + pq, j, sB, tB);
      {
        float2 o = *(const float2*)&ol[(24 + pq) * OCOFF + 2 * c];
        tB = mk_tapd(o.x, o.y, h, wbase + 24 + pq, c);
        issueD(sB, xb, tB, j4);
      }
      consumeD(mh, ml, 16 + pq, j, sA, tA);
      if (c < 8) {
        float2 o = *(const float2*)&ol[pq * OCOFF + 2 * (c + 1)];
        tA = mk_tapd(o.x, o.y, h, wbase + pq, c + 1);
        issueD(sA, xb, tA, j4);
      }
      consumeD(mh, ml, 24 + pq, j, sB, tB);
      // phase B: B-frags from LDS, 6 MFMA per kstep (2 o-tiles x hi/lo)
#pragma unroll
      for (int s = 0; s < 4; ++s) {
        int ridx = P * SMP_STRIDE + s * 8 + g * 4;
        short8 sh8 = *(const short8*)&mh[ridx];
        short8 sl8 = *(const short8*)&ml[ridx];
        const unsigned* wb = wfrag + ((size_t)((c * 16 + s * 2) * 64 + l)) * 4;
        short8 wh0 = *(const short8*)(wb);
        short8 wl0 = *(const short8*)(wb + 256);
        short8 wh1 = *(const short8*)(wb + 2048);
        short8 wl1 = *(const short8*)(wb + 2304);
        acc0 = __builtin_amdgcn_mfma_f32_32x32x16_bf16(wh0, sh8, acc0, 0, 0, 0);
        acc0 = __builtin_amdgcn_mfma_f32_32x32x16_bf16(wh0, sl8, acc0, 0, 0, 0);
        acc0 = __builtin_amdgcn_mfma_f32_32x32x16_bf16(wl0, sh8, acc0, 0, 0, 0);
        acc1 = __builtin_amdgcn_mfma_f32_32x32x16_bf16(wh1, sh8, acc1, 0, 0, 0);
        acc1 = __builtin_amdgcn_mfma_f32_32x32x16_bf16(wh1, sl8, acc1, 0, 0, 0);
        acc1 = __builtin_amdgcn_mfma_f32_32x32x16_bf16(wl1, sh8, acc1, 0, 0, 0);
      }
    }
  }

  // epilogue: bias + store (validated layout)
  const int wpix = wbase + P;
#pragma unroll
  for (int r = 0; r < 16; ++r) {
    int o0 = (r & 3) + 8 * (r >> 2) + 4 * g;
    out[(((size_t)b * 64 + o0) * 128 + h) * 128 + wpix] = acc0[r] + bias[o0];
    out[(((size_t)b * 64 + 32 + o0) * 128 + h) * 128 + wpix] = acc1[r] + bias[32 + o0];
  }
}

// ---------------------------------------------------------------------------
extern "C" void kernel_launch(void* const* d_in, const int* in_sizes, int n_in,
                              void* d_out, int out_size, void* d_ws, size_t ws_size,
                              hipStream_t stream) {
  const float* x      = (const float*)d_in[0];
  const float* w_off  = (const float*)d_in[1];
  const float* b_off  = (const float*)d_in[2];
  const float* weight = (const float*)d_in[3];
  const float* bias   = (const float*)d_in[4];
  float* out = (float*)d_out;

  // workspace: xt | wfrag | wofrag  (~17 MB)
  float*    xt     = (float*)d_ws;                 // 4*128*128*64 = 4,194,304 f
  unsigned* wfrag  = (unsigned*)(xt + (size_t)4194304);  // 36,864 dw
  unsigned* wofrag = wfrag + 36864;                // 18,432 dw

  prep_wfrag<<<144, 256, 0, stream>>>(weight, wfrag);
  prep_wofrag<<<72, 256, 0, stream>>>(w_off, wofrag);
  transpose_x<<<2048, 256, 0, stream>>>(x, xt);

  fused_deform<<<1024, 128, 0, stream>>>(xt, wfrag, wofrag, b_off, bias, out);
}

// Round 8
// 146.505 us; speedup vs baseline: 1.4640x; 1.0258x over previous
//
#include <hip/hip_runtime.h>
#include <hip/hip_bf16.h>

// Problem constants: B=4, C=64, O=64, H=W=128, K=3, PAD=1
#define BB 4
#define CC 64
#define OO 64
#define HH 128
#define WW 128
#define HW (HH * WW)       // 16384
#define K2 9
#define OCOFF 18           // 2*K2 offset channels
#define SMP_STRIDE 36      // u32 per px row in LDS (32 data + 4 pad)

typedef __attribute__((ext_vector_type(8))) short short8;     // 8 bf16 = 4 VGPR
typedef __attribute__((ext_vector_type(16))) float f32x16;    // MFMA 32x32 acc

union U8 { unsigned u[4]; short8 s8; };

__device__ __forceinline__ float uf(unsigned u) { return __builtin_bit_cast(float, u); }

// packed f32->bf16 via HW cvt: dst[15:0]=bf16(a), dst[31:16]=bf16(b)
__device__ __forceinline__ unsigned cvtpk(float a, float b) {
  unsigned r;
  asm("v_cvt_pk_bf16_f32 %0, %1, %2" : "=v"(r) : "v"(a), "v"(b));
  return r;
}
// hi/lo split of a value pair: ph = packed hi bf16s, pl = packed residual bf16s
__device__ __forceinline__ void split2(float a, float b, unsigned& ph, unsigned& pl) {
  ph = cvtpk(a, b);
  float ra = a - uf(ph << 16);
  float rb = b - uf(ph & 0xFFFF0000u);
  pl = cvtpk(ra, rb);
}

// RNE float->bf16 bit-twiddle (prep kernels only; validated r4-r7)
__device__ __forceinline__ unsigned short bf16_rne(float v) {
  unsigned u = __builtin_bit_cast(unsigned, v);
  return (unsigned short)((u + 0x7FFFu + ((u >> 16) & 1u)) >> 16);
}
__device__ __forceinline__ void bf16_split(float v, unsigned short& hi, unsigned short& lo) {
  hi = bf16_rne(v);
  float hf = __builtin_bit_cast(float, (unsigned)hi << 16);
  lo = bf16_rne(v - hf);
}
__device__ __forceinline__ float4 ld4(const float* p) { return *(const float4*)p; }

// ---------------------------------------------------------------------------
// prep_all: one kernel, three block-ranges.
//   [0,2048)      : NCHW -> NHWC transpose (validated r4-r7)
//   [2048,2192)   : wfrag  (main-weight A-fragments, validated r4-r7)
//   [2192,2264)   : wofrag (offset-weight A-fragments, validated r5-r7)
// ---------------------------------------------------------------------------
__global__ __launch_bounds__(256) void prep_all(
    const float* __restrict__ x, const float* __restrict__ weight,
    const float* __restrict__ w_off, float* __restrict__ xt,
    unsigned* __restrict__ wf, unsigned* __restrict__ wof) {
  int blk = blockIdx.x;
  int t = threadIdx.x;
  if (blk < 2048) {
    __shared__ float tile[64][33];
    int wt = blk & 3, h = (blk >> 2) & 127, b = blk >> 9;
    int w0 = wt * 32;
    {
      int w_l = t & 31, c_l = t >> 5;
#pragma unroll
      for (int i = 0; i < 8; ++i) {
        int cc = c_l * 8 + i;
        tile[cc][w_l] = x[(((size_t)b * 64 + cc) * 128 + h) * 128 + w0 + w_l];
      }
    }
    __syncthreads();
    {
      int c_w = t & 63, w_w = t >> 6;
#pragma unroll
      for (int i = 0; i < 8; ++i) {
        int wl = w_w * 8 + i;
        xt[(((size_t)b * 128 + h) * 128 + w0 + wl) * 64 + c_w] = tile[c_w][wl];
      }
    }
    return;
  }
  if (blk < 2048 + 144) {
    int d = (blk - 2048) * 256 + t;
    if (d >= 9 * 4096) return;
    int j2 = d & 3, l = (d >> 2) & 63, hh = (d >> 8) & 1, s = (d >> 9) & 3,
        m = (d >> 11) & 1, c = d >> 12;
    int o = m * 32 + (l & 31);
    int g = l >> 5;
    int ch0 = s * 16 + g * 8 + j2 * 2;
    float v0 = weight[(o * 64 + ch0) * 9 + c];
    float v1 = weight[(o * 64 + ch0 + 1) * 9 + c];
    unsigned short h0, l0, h1, l1;
    bf16_split(v0, h0, l0);
    bf16_split(v1, h1, l1);
    unsigned short b0 = hh ? l0 : h0;
    unsigned short b1 = hh ? l1 : h1;
    wf[d] = (unsigned)b0 | ((unsigned)b1 << 16);
    return;
  }
  {
    int d = (blk - 2192) * 256 + t;
    if (d >= 9 * 2048) return;
    int j2 = d & 3, l = (d >> 2) & 63, hh = (d >> 8) & 1, s = (d >> 9) & 3,
        c = d >> 11;
    int oc = l & 31;
    int g = l >> 5;
    int ch0 = s * 16 + g * 8 + j2 * 2;
    unsigned r = 0;
    if (oc < OCOFF) {
      float v0 = w_off[(oc * 64 + ch0) * 9 + c];
      float v1 = w_off[(oc * 64 + ch0 + 1) * 9 + c];
      unsigned short h0, l0, h1, l1;
      bf16_split(v0, h0, l0);
      bf16_split(v1, h1, l1);
      unsigned short b0 = hh ? l0 : h0;
      unsigned short b1 = hh ? l1 : h1;
      r = (unsigned)b0 | ((unsigned)b1 << 16);
    }
    wof[d] = r;
    return;
  }
}

// ---------------------------------------------------------------------------
// tap descriptor for deformable taps (validated r4-r7)
// ---------------------------------------------------------------------------
struct TapD { int o00, o01, o10, o11; float w00, w01, w10, w11; };

__device__ __forceinline__ TapD mk_tapd(float oyv, float oxv, int h, int wpix, int kk) {
  TapD t;
  const int dy = kk / 3 - 1, dx = kk - (kk / 3) * 3 - 1;
  float py = oyv + (float)(h + dy);
  float px = oxv + (float)(wpix + dx);
  float y0f = floorf(py), x0f = floorf(px);
  float wy1 = py - y0f, wx1 = px - x0f;
  float wy0 = 1.0f - wy1, wx0 = 1.0f - wx1;
  int y0 = (int)y0f, x0 = (int)x0f, y1 = y0 + 1, x1 = x0 + 1;
  bool vy0 = (unsigned)y0 < (unsigned)HH, vy1 = (unsigned)y1 < (unsigned)HH;
  bool vx0 = (unsigned)x0 < (unsigned)WW, vx1 = (unsigned)x1 < (unsigned)WW;
  t.w00 = (vy0 && vx0) ? wy0 * wx0 : 0.0f;
  t.w01 = (vy0 && vx1) ? wy0 * wx1 : 0.0f;
  t.w10 = (vy1 && vx0) ? wy1 * wx0 : 0.0f;
  t.w11 = (vy1 && vx1) ? wy1 * wx1 : 0.0f;
  int y0c = min(max(y0, 0), HH - 1), y1c = min(max(y1, 0), HH - 1);
  int x0c = min(max(x0, 0), WW - 1), x1c = min(max(x1, 0), WW - 1);
  t.o00 = (y0c * WW + x0c) * CC;
  t.o01 = (y0c * WW + x1c) * CC;
  t.o10 = (y1c * WW + x0c) * CC;
  t.o11 = (y1c * WW + x1c) * CC;
  return t;
}

// ---------------------------------------------------------------------------
// phase-2 gather-transpose helpers (lane map: j = l&7 ch-granule, pq = l>>3 px)
// ---------------------------------------------------------------------------
__device__ __forceinline__ void issueD(float4 (&st)[8], const float* xb,
                                       const TapD& t, int j4) {
  st[0] = ld4(xb + t.o00 + j4);      st[1] = ld4(xb + t.o01 + j4);
  st[2] = ld4(xb + t.o10 + j4);      st[3] = ld4(xb + t.o11 + j4);
  st[4] = ld4(xb + t.o00 + 32 + j4); st[5] = ld4(xb + t.o01 + 32 + j4);
  st[6] = ld4(xb + t.o10 + 32 + j4); st[7] = ld4(xb + t.o11 + 32 + j4);
}

__device__ __forceinline__ void consumeD(unsigned* mh, unsigned* ml,
                                         int pl, int j,
                                         const float4 (&st)[8], const TapD& t) {
#pragma unroll
  for (int hf = 0; hf < 2; ++hf) {
    float v[4];
#pragma unroll
    for (int q = 0; q < 4; ++q)
      v[q] = fmaf(t.w00, st[hf * 4 + 0][q], fmaf(t.w01, st[hf * 4 + 1][q],
             fmaf(t.w10, st[hf * 4 + 2][q], t.w11 * st[hf * 4 + 3][q])));
    unsigned h01, l01, h23, l23;
    split2(v[0], v[1], h01, l01);
    split2(v[2], v[3], h23, l23);
    int idx = pl * SMP_STRIDE + hf * 16 + j * 2;
    *(uint2*)&mh[idx] = make_uint2(h01, h23);
    *(uint2*)&ml[idx] = make_uint2(l01, l23);
  }
}

// ---------------------------------------------------------------------------
// fused kernel. Block = 128 thr = 2 independent waves (no barriers).
// Phase 1: offset conv — B-fragments loaded DIRECTLY from global f32 rows
//          (lane l: px = wbase+(l&31), ch granule (l>>5)), masked, cvt_pk
//          split in registers. 12 MFMA/tap, no LDS.
// Phase 2: deformable sampling (gather-transpose via wave-private LDS) +
//          main einsum, 24 MFMA/tap. cvt_pk splits.
// ---------------------------------------------------------------------------
__global__ __launch_bounds__(128, 2) void fused_deform(
    const float* __restrict__ xt, const unsigned* __restrict__ wfrag,
    const unsigned* __restrict__ wofrag, const float* __restrict__ b_off,
    const float* __restrict__ bias, float* __restrict__ out) {
  __shared__ __align__(16) unsigned smph[2][32 * SMP_STRIDE];
  __shared__ __align__(16) unsigned smpl[2][32 * SMP_STRIDE];
  __shared__ __align__(16) float offs_lds[2][32 * OCOFF];

  const int blk = blockIdx.x;
  const int sx = (blk & 7) * 128 + (blk >> 3);   // bijective: 1024 % 8 == 0
  const int seg = sx & 1, h = (sx >> 1) & 127, b = sx >> 8;
  const int tid = threadIdx.x;
  const int l = tid & 63, wv = tid >> 6;
  const int P = l & 31, g = l >> 5;
  const int j = l & 7, pq = l >> 3;
  const int j4 = j * 4;
  const int wbase = seg * 64 + wv * 32;          // w coord of wave's px 0

  const float* xb = xt + (size_t)b * HW * CC;
  unsigned* mh = smph[wv];
  unsigned* ml = smpl[wv];
  float* ol = offs_lds[wv];

  // ======================= PHASE 1: offset conv =======================
  {
    f32x16 accO = {0,0,0,0,0,0,0,0,0,0,0,0,0,0,0,0};
#pragma unroll
    for (int c = 0; c < 9; ++c) {
      const int dy = c / 3 - 1, dx = c - (c / 3) * 3 - 1;
      const int y = h + dy;
      const int xp = wbase + P + dx;
      const bool valid = ((unsigned)y < (unsigned)HH) && ((unsigned)xp < (unsigned)WW);
      const unsigned msk = valid ? 0xFFFFFFFFu : 0u;
      const int yc = min(max(y, 0), HH - 1), xc = min(max(xp, 0), WW - 1);
      const unsigned* rowp = (const unsigned*)(xb + (size_t)(yc * WW + xc) * CC);
#pragma unroll
      for (int s = 0; s < 4; ++s) {
        const int cb = s * 16 + g * 8;
        uint4 u0 = *(const uint4*)(rowp + cb);
        uint4 u1 = *(const uint4*)(rowp + cb + 4);
        u0.x &= msk; u0.y &= msk; u0.z &= msk; u0.w &= msk;
        u1.x &= msk; u1.y &= msk; u1.z &= msk; u1.w &= msk;
        U8 sh, sl;
        split2(uf(u0.x), uf(u0.y), sh.u[0], sl.u[0]);
        split2(uf(u0.z), uf(u0.w), sh.u[1], sl.u[1]);
        split2(uf(u1.x), uf(u1.y), sh.u[2], sl.u[2]);
        split2(uf(u1.z), uf(u1.w), sh.u[3], sl.u[3]);
        const unsigned* wb = wofrag + ((size_t)((c * 8 + s * 2) * 64 + l)) * 4;
        short8 wh = *(const short8*)(wb);
        short8 wl = *(const short8*)(wb + 256);
        accO = __builtin_amdgcn_mfma_f32_32x32x16_bf16(wh, sh.s8, accO, 0, 0, 0);
        accO = __builtin_amdgcn_mfma_f32_32x32x16_bf16(wh, sl.s8, accO, 0, 0, 0);
        accO = __builtin_amdgcn_mfma_f32_32x32x16_bf16(wl, sh.s8, accO, 0, 0, 0);
      }
    }
    // park offsets in LDS: D layout col=P, row=(r&3)+8*(r>>2)+4g (validated)
#pragma unroll
    for (int r = 0; r < 16; ++r) {
      int oc = (r & 3) + 8 * (r >> 2) + 4 * g;
      if (oc < OCOFF) ol[P * OCOFF + oc] = accO[r] + b_off[oc];
    }
  }

  // ======================= PHASE 2: deformable conv ====================
  f32x16 acc0 = {0,0,0,0,0,0,0,0,0,0,0,0,0,0,0,0};
  f32x16 acc1 = {0,0,0,0,0,0,0,0,0,0,0,0,0,0,0,0};
  {
    TapD tA, tB;
    float4 sA[8], sB[8];
    {
      float2 o = *(const float2*)&ol[pq * OCOFF + 0];
      tA = mk_tapd(o.x, o.y, h, wbase + pq, 0);
      issueD(sA, xb, tA, j4);
    }
#pragma unroll
    for (int c = 0; c < 9; ++c) {
      {
        float2 o = *(const float2*)&ol[(8 + pq) * OCOFF + 2 * c];
        tB = mk_tapd(o.x, o.y, h, wbase + 8 + pq, c);
        issueD(sB, xb, tB, j4);
      }
      consumeD(mh, ml, pq, j, sA, tA);
      {
        float2 o = *(const float2*)&ol[(16 + pq) * OCOFF + 2 * c];
        tA = mk_tapd(o.x, o.y, h, wbase + 16 + pq, c);
        issueD(sA, xb, tA, j4);
      }
      consumeD(mh, ml, 8 + pq, j, sB, tB);
      {
        float2 o = *(const float2*)&ol[(24 + pq) * OCOFF + 2 * c];
        tB = mk_tapd(o.x, o.y, h, wbase + 24 + pq, c);
        issueD(sB, xb, tB, j4);
      }
      consumeD(mh, ml, 16 + pq, j, sA, tA);
      if (c < 8) {
        float2 o = *(const float2*)&ol[pq * OCOFF + 2 * (c + 1)];
        tA = mk_tapd(o.x, o.y, h, wbase + pq, c + 1);
        issueD(sA, xb, tA, j4);
      }
      consumeD(mh, ml, 24 + pq, j, sB, tB);
      // B-frags from LDS, 6 MFMA per kstep (2 o-tiles x hi/lo 3-term)
#pragma unroll
      for (int s = 0; s < 4; ++s) {
        int ridx = P * SMP_STRIDE + s * 8 + g * 4;
        short8 sh8 = *(const short8*)&mh[ridx];
        short8 sl8 = *(const short8*)&ml[ridx];
        const unsigned* wb = wfrag + ((size_t)((c * 16 + s * 2) * 64 + l)) * 4;
        short8 wh0 = *(const short8*)(wb);
        short8 wl0 = *(const short8*)(wb + 256);
        short8 wh1 = *(const short8*)(wb + 2048);
        short8 wl1 = *(const short8*)(wb + 2304);
        acc0 = __builtin_amdgcn_mfma_f32_32x32x16_bf16(wh0, sh8, acc0, 0, 0, 0);
        acc0 = __builtin_amdgcn_mfma_f32_32x32x16_bf16(wh0, sl8, acc0, 0, 0, 0);
        acc0 = __builtin_amdgcn_mfma_f32_32x32x16_bf16(wl0, sh8, acc0, 0, 0, 0);
        acc1 = __builtin_amdgcn_mfma_f32_32x32x16_bf16(wh1, sh8, acc1, 0, 0, 0);
        acc1 = __builtin_amdgcn_mfma_f32_32x32x16_bf16(wh1, sl8, acc1, 0, 0, 0);
        acc1 = __builtin_amdgcn_mfma_f32_32x32x16_bf16(wl1, sh8, acc1, 0, 0, 0);
      }
    }
  }

  // epilogue: bias + store (validated layout)
  const int wpix = wbase + P;
#pragma unroll
  for (int r = 0; r < 16; ++r) {
    int o0 = (r & 3) + 8 * (r >> 2) + 4 * g;
    out[(((size_t)b * 64 + o0) * 128 + h) * 128 + wpix] = acc0[r] + bias[o0];
    out[(((size_t)b * 64 + 32 + o0) * 128 + h) * 128 + wpix] = acc1[r] + bias[32 + o0];
  }
}

// ---------------------------------------------------------------------------
extern "C" void kernel_launch(void* const* d_in, const int* in_sizes, int n_in,
                              void* d_out, int out_size, void* d_ws, size_t ws_size,
                              hipStream_t stream) {
  const float* x      = (const float*)d_in[0];
  const float* w_off  = (const float*)d_in[1];
  const float* b_off  = (const float*)d_in[2];
  const float* weight = (const float*)d_in[3];
  const float* bias   = (const float*)d_in[4];
  float* out = (float*)d_out;

  // workspace: xt | wfrag | wofrag  (~17 MB, same as r7 proven size)
  float*    xt     = (float*)d_ws;                       // 4,194,304 f
  unsigned* wfrag  = (unsigned*)(xt + (size_t)4194304);  // 36,864 dw
  unsigned* wofrag = wfrag + 36864;                      // 18,432 dw

  prep_all<<<2264, 256, 0, stream>>>(x, weight, w_off, xt, wfrag, wofrag);
  fused_deform<<<1024, 128, 0, stream>>>(xt, wfrag, wofrag, b_off, bias, out);
}

// Round 9
// 136.076 us; speedup vs baseline: 1.5762x; 1.0766x over previous
//
#include <hip/hip_runtime.h>
#include <hip/hip_bf16.h>

// Problem constants: B=4, C=64, O=64, H=W=128, K=3, PAD=1
#define BB 4
#define CC 64
#define OO 64
#define HH 128
#define WW 128
#define HW (HH * WW)       // 16384
#define K2 9
#define OCOFF 18           // 2*K2 offset channels
#define SMP_STRIDE 36      // u32 per px row in LDS (32 data + 4 pad)

typedef __attribute__((ext_vector_type(8))) short short8;     // 8 bf16 = 4 VGPR
typedef __attribute__((ext_vector_type(16))) float f32x16;    // MFMA 32x32 acc

union U8 { unsigned u[4]; short8 s8; };

__device__ __forceinline__ float uf(unsigned u) { return __builtin_bit_cast(float, u); }

// packed f32->bf16 via HW cvt: dst[15:0]=bf16(a), dst[31:16]=bf16(b)
__device__ __forceinline__ unsigned cvtpk(float a, float b) {
  unsigned r;
  asm("v_cvt_pk_bf16_f32 %0, %1, %2" : "=v"(r) : "v"(a), "v"(b));
  return r;
}
// hi/lo split of a value pair: ph = packed hi bf16s, pl = packed residual bf16s
__device__ __forceinline__ void split2(float a, float b, unsigned& ph, unsigned& pl) {
  ph = cvtpk(a, b);
  float ra = a - uf(ph << 16);
  float rb = b - uf(ph & 0xFFFF0000u);
  pl = cvtpk(ra, rb);
}

// RNE float->bf16 bit-twiddle (prep kernel only; validated r4-r8)
__device__ __forceinline__ unsigned short bf16_rne(float v) {
  unsigned u = __builtin_bit_cast(unsigned, v);
  return (unsigned short)((u + 0x7FFFu + ((u >> 16) & 1u)) >> 16);
}
__device__ __forceinline__ void bf16_split(float v, unsigned short& hi, unsigned short& lo) {
  hi = bf16_rne(v);
  float hf = __builtin_bit_cast(float, (unsigned)hi << 16);
  lo = bf16_rne(v - hf);
}
__device__ __forceinline__ float4 ld4(const float* p) { return *(const float4*)p; }

// ---------------------------------------------------------------------------
// prep_all: one kernel, three block-ranges (all validated r4-r8).
// ---------------------------------------------------------------------------
__global__ __launch_bounds__(256) void prep_all(
    const float* __restrict__ x, const float* __restrict__ weight,
    const float* __restrict__ w_off, float* __restrict__ xt,
    unsigned* __restrict__ wf, unsigned* __restrict__ wof) {
  int blk = blockIdx.x;
  int t = threadIdx.x;
  if (blk < 2048) {
    __shared__ float tile[64][33];
    int wt = blk & 3, h = (blk >> 2) & 127, b = blk >> 9;
    int w0 = wt * 32;
    {
      int w_l = t & 31, c_l = t >> 5;
#pragma unroll
      for (int i = 0; i < 8; ++i) {
        int cc = c_l * 8 + i;
        tile[cc][w_l] = x[(((size_t)b * 64 + cc) * 128 + h) * 128 + w0 + w_l];
      }
    }
    __syncthreads();
    {
      int c_w = t & 63, w_w = t >> 6;
#pragma unroll
      for (int i = 0; i < 8; ++i) {
        int wl = w_w * 8 + i;
        xt[(((size_t)b * 128 + h) * 128 + w0 + wl) * 64 + c_w] = tile[c_w][wl];
      }
    }
    return;
  }
  if (blk < 2048 + 144) {
    int d = (blk - 2048) * 256 + t;
    if (d >= 9 * 4096) return;
    int j2 = d & 3, l = (d >> 2) & 63, hh = (d >> 8) & 1, s = (d >> 9) & 3,
        m = (d >> 11) & 1, c = d >> 12;
    int o = m * 32 + (l & 31);
    int g = l >> 5;
    int ch0 = s * 16 + g * 8 + j2 * 2;
    float v0 = weight[(o * 64 + ch0) * 9 + c];
    float v1 = weight[(o * 64 + ch0 + 1) * 9 + c];
    unsigned short h0, l0, h1, l1;
    bf16_split(v0, h0, l0);
    bf16_split(v1, h1, l1);
    unsigned short b0 = hh ? l0 : h0;
    unsigned short b1 = hh ? l1 : h1;
    wf[d] = (unsigned)b0 | ((unsigned)b1 << 16);
    return;
  }
  {
    int d = (blk - 2192) * 256 + t;
    if (d >= 9 * 2048) return;
    int j2 = d & 3, l = (d >> 2) & 63, hh = (d >> 8) & 1, s = (d >> 9) & 3,
        c = d >> 11;
    int oc = l & 31;
    int g = l >> 5;
    int ch0 = s * 16 + g * 8 + j2 * 2;
    unsigned r = 0;
    if (oc < OCOFF) {
      float v0 = w_off[(oc * 64 + ch0) * 9 + c];
      float v1 = w_off[(oc * 64 + ch0 + 1) * 9 + c];
      unsigned short h0, l0, h1, l1;
      bf16_split(v0, h0, l0);
      bf16_split(v1, h1, l1);
      unsigned short b0 = hh ? l0 : h0;
      unsigned short b1 = hh ? l1 : h1;
      r = (unsigned)b0 | ((unsigned)b1 << 16);
    }
    wof[d] = r;
    return;
  }
}

// ---------------------------------------------------------------------------
// tap descriptor (validated r4-r8)
// ---------------------------------------------------------------------------
struct TapD { int o00, o01, o10, o11; float w00, w01, w10, w11; };
struct TapW { float w00, w01, w10, w11; };

__device__ __forceinline__ TapD mk_tapd(float oyv, float oxv, int h, int wpix, int kk) {
  TapD t;
  const int dy = kk / 3 - 1, dx = kk - (kk / 3) * 3 - 1;
  float py = oyv + (float)(h + dy);
  float px = oxv + (float)(wpix + dx);
  float y0f = floorf(py), x0f = floorf(px);
  float wy1 = py - y0f, wx1 = px - x0f;
  float wy0 = 1.0f - wy1, wx0 = 1.0f - wx1;
  int y0 = (int)y0f, x0 = (int)x0f, y1 = y0 + 1, x1 = x0 + 1;
  bool vy0 = (unsigned)y0 < (unsigned)HH, vy1 = (unsigned)y1 < (unsigned)HH;
  bool vx0 = (unsigned)x0 < (unsigned)WW, vx1 = (unsigned)x1 < (unsigned)WW;
  t.w00 = (vy0 && vx0) ? wy0 * wx0 : 0.0f;
  t.w01 = (vy0 && vx1) ? wy0 * wx1 : 0.0f;
  t.w10 = (vy1 && vx0) ? wy1 * wx0 : 0.0f;
  t.w11 = (vy1 && vx1) ? wy1 * wx1 : 0.0f;
  int y0c = min(max(y0, 0), HH - 1), y1c = min(max(y1, 0), HH - 1);
  int x0c = min(max(x0, 0), WW - 1), x1c = min(max(x1, 0), WW - 1);
  t.o00 = (y0c * WW + x0c) * CC;
  t.o01 = (y0c * WW + x1c) * CC;
  t.o10 = (y1c * WW + x0c) * CC;
  t.o11 = (y1c * WW + x1c) * CC;
  return t;
}

// ---------------------------------------------------------------------------
// phase-2 pipeline pieces. Lane map: j = l&7 (ch granule), pq = l>>3 (px).
// stageD2: issue 8 ld4 for round r of tap c (px = wbase + r*8 + pq).
// ---------------------------------------------------------------------------
__device__ __forceinline__ TapW stageD2(float4 (&st)[8], const float* xb,
                                        const float* ol, int h, int wbase,
                                        int pq, int j4, int r, int c) {
  float2 o = *(const float2*)&ol[(r * 8 + pq) * OCOFF + 2 * c];
  TapD t = mk_tapd(o.x, o.y, h, wbase + r * 8 + pq, c);
  st[0] = ld4(xb + t.o00 + j4);      st[1] = ld4(xb + t.o01 + j4);
  st[2] = ld4(xb + t.o10 + j4);      st[3] = ld4(xb + t.o11 + j4);
  st[4] = ld4(xb + t.o00 + 32 + j4); st[5] = ld4(xb + t.o01 + 32 + j4);
  st[6] = ld4(xb + t.o10 + 32 + j4); st[7] = ld4(xb + t.o11 + 32 + j4);
  TapW w = { t.w00, t.w01, t.w10, t.w11 };
  return w;
}

__device__ __forceinline__ void consD(unsigned* mh, unsigned* ml,
                                      int pl, int j,
                                      const float4 (&st)[8], const TapW& t) {
#pragma unroll
  for (int hf = 0; hf < 2; ++hf) {
    float v[4];
#pragma unroll
    for (int q = 0; q < 4; ++q)
      v[q] = fmaf(t.w00, st[hf * 4 + 0][q], fmaf(t.w01, st[hf * 4 + 1][q],
             fmaf(t.w10, st[hf * 4 + 2][q], t.w11 * st[hf * 4 + 3][q])));
    unsigned h01, l01, h23, l23;
    split2(v[0], v[1], h01, l01);
    split2(v[2], v[3], h23, l23);
    int idx = pl * SMP_STRIDE + hf * 16 + j * 2;
    *(uint2*)&mh[idx] = make_uint2(h01, h23);
    *(uint2*)&ml[idx] = make_uint2(l01, l23);
  }
}

__device__ __forceinline__ void p2_mfma(f32x16& acc0, f32x16& acc1,
                                        const unsigned* mh, const unsigned* ml,
                                        const unsigned* wfrag,
                                        int P, int g, int l, int c) {
  __builtin_amdgcn_s_setprio(1);
#pragma unroll
  for (int s = 0; s < 4; ++s) {
    int ridx = P * SMP_STRIDE + s * 8 + g * 4;
    short8 sh8 = *(const short8*)&mh[ridx];
    short8 sl8 = *(const short8*)&ml[ridx];
    const unsigned* wb = wfrag + ((size_t)((c * 16 + s * 2) * 64 + l)) * 4;
    short8 wh0 = *(const short8*)(wb);
    short8 wl0 = *(const short8*)(wb + 256);
    short8 wh1 = *(const short8*)(wb + 2048);
    short8 wl1 = *(const short8*)(wb + 2304);
    acc0 = __builtin_amdgcn_mfma_f32_32x32x16_bf16(wh0, sh8, acc0, 0, 0, 0);
    acc0 = __builtin_amdgcn_mfma_f32_32x32x16_bf16(wh0, sl8, acc0, 0, 0, 0);
    acc0 = __builtin_amdgcn_mfma_f32_32x32x16_bf16(wl0, sh8, acc0, 0, 0, 0);
    acc1 = __builtin_amdgcn_mfma_f32_32x32x16_bf16(wh1, sh8, acc1, 0, 0, 0);
    acc1 = __builtin_amdgcn_mfma_f32_32x32x16_bf16(wh1, sl8, acc1, 0, 0, 0);
    acc1 = __builtin_amdgcn_mfma_f32_32x32x16_bf16(wl1, sh8, acc1, 0, 0, 0);
  }
  __builtin_amdgcn_s_setprio(0);
}

// ---------------------------------------------------------------------------
// phase-1 pieces: direct B-fragment load (lane l: px = wbase+P, granule g).
// ---------------------------------------------------------------------------
__device__ __forceinline__ unsigned stageO1(uint4 (&T)[8], const float* xb,
                                            int h, int wP, int g, int c) {
  const int dy = c / 3 - 1, dx = c - (c / 3) * 3 - 1;
  const int y = h + dy, xp = wP + dx;
  bool valid = ((unsigned)y < (unsigned)HH) && ((unsigned)xp < (unsigned)WW);
  int yc = min(max(y, 0), HH - 1), xc = min(max(xp, 0), WW - 1);
  const uint4* rowp = (const uint4*)(xb + (size_t)(yc * WW + xc) * CC);
#pragma unroll
  for (int s = 0; s < 4; ++s) {
    T[2 * s]     = rowp[s * 4 + g * 2];
    T[2 * s + 1] = rowp[s * 4 + g * 2 + 1];
  }
  return valid ? 0xFFFFFFFFu : 0u;
}

__device__ __forceinline__ void p1_tap(f32x16& accO, uint4 (&TC)[8], unsigned mskC,
                                       uint4 (&TN)[8], unsigned& mskN,
                                       const float* xb, const unsigned* wofrag,
                                       int h, int wP, int g, int l, int c, bool last) {
  if (!last) {
    mskN = stageO1(TN, xb, h, wP, g, c + 1);
    __builtin_amdgcn_sched_barrier(0);
  }
#pragma unroll
  for (int s = 0; s < 4; ++s) {
    uint4 u0 = TC[2 * s], u1 = TC[2 * s + 1];
    u0.x &= mskC; u0.y &= mskC; u0.z &= mskC; u0.w &= mskC;
    u1.x &= mskC; u1.y &= mskC; u1.z &= mskC; u1.w &= mskC;
    U8 sh, sl;
    split2(uf(u0.x), uf(u0.y), sh.u[0], sl.u[0]);
    split2(uf(u0.z), uf(u0.w), sh.u[1], sl.u[1]);
    split2(uf(u1.x), uf(u1.y), sh.u[2], sl.u[2]);
    split2(uf(u1.z), uf(u1.w), sh.u[3], sl.u[3]);
    const unsigned* wb = wofrag + ((size_t)((c * 8 + s * 2) * 64 + l)) * 4;
    short8 wh = *(const short8*)(wb);
    short8 wl = *(const short8*)(wb + 256);
    __builtin_amdgcn_s_setprio(1);
    accO = __builtin_amdgcn_mfma_f32_32x32x16_bf16(wh, sh.s8, accO, 0, 0, 0);
    accO = __builtin_amdgcn_mfma_f32_32x32x16_bf16(wh, sl.s8, accO, 0, 0, 0);
    accO = __builtin_amdgcn_mfma_f32_32x32x16_bf16(wl, sh.s8, accO, 0, 0, 0);
    __builtin_amdgcn_s_setprio(0);
  }
}

// ---------------------------------------------------------------------------
// phase-2 tap body: 4-buffer round pipeline with sched_barrier pinning.
// ---------------------------------------------------------------------------
__device__ __forceinline__ void p2_tap(
    f32x16& acc0, f32x16& acc1,
    float4 (&S0)[8], float4 (&S1)[8], float4 (&S2)[8], float4 (&S3)[8],
    TapW& t0, TapW& t1, TapW& t2, TapW& t3,
    unsigned* mh, unsigned* ml, const float* xb, const float* ol,
    const unsigned* wfrag, int h, int wbase, int pq, int j, int j4,
    int P, int g, int l, int c, bool last) {
  t2 = stageD2(S2, xb, ol, h, wbase, pq, j4, 2, c);
  __builtin_amdgcn_sched_barrier(0);
  consD(mh, ml, 0 * 8 + pq, j, S0, t0);
  t3 = stageD2(S3, xb, ol, h, wbase, pq, j4, 3, c);
  __builtin_amdgcn_sched_barrier(0);
  consD(mh, ml, 1 * 8 + pq, j, S1, t1);
  if (!last) {
    t0 = stageD2(S0, xb, ol, h, wbase, pq, j4, 0, c + 1);
    __builtin_amdgcn_sched_barrier(0);
  }
  consD(mh, ml, 2 * 8 + pq, j, S2, t2);
  if (!last) {
    t1 = stageD2(S1, xb, ol, h, wbase, pq, j4, 1, c + 1);
    __builtin_amdgcn_sched_barrier(0);
  }
  consD(mh, ml, 3 * 8 + pq, j, S3, t3);
  p2_mfma(acc0, acc1, mh, ml, wfrag, P, g, l, c);
}

// ---------------------------------------------------------------------------
// fused kernel. Block = 128 thr = 2 independent waves (no barriers).
// ---------------------------------------------------------------------------
__global__ __launch_bounds__(128, 2) void fused_deform(
    const float* __restrict__ xt, const unsigned* __restrict__ wfrag,
    const unsigned* __restrict__ wofrag, const float* __restrict__ b_off,
    const float* __restrict__ bias, float* __restrict__ out) {
  __shared__ __align__(16) unsigned smph[2][32 * SMP_STRIDE];
  __shared__ __align__(16) unsigned smpl[2][32 * SMP_STRIDE];
  __shared__ __align__(16) float offs_lds[2][32 * OCOFF];

  const int blk = blockIdx.x;
  const int sx = (blk & 7) * 128 + (blk >> 3);   // bijective: 1024 % 8 == 0
  const int seg = sx & 1, h = (sx >> 1) & 127, b = sx >> 8;
  const int tid = threadIdx.x;
  const int l = tid & 63, wv = tid >> 6;
  const int P = l & 31, g = l >> 5;
  const int j = l & 7, pq = l >> 3;
  const int j4 = j * 4;
  const int wbase = seg * 64 + wv * 32;          // w coord of wave's px 0

  const float* xb = xt + (size_t)b * HW * CC;
  unsigned* mh = smph[wv];
  unsigned* ml = smpl[wv];
  float* ol = offs_lds[wv];

  // ======================= PHASE 1: offset conv =======================
  {
    f32x16 accO = {0,0,0,0,0,0,0,0,0,0,0,0,0,0,0,0};
    uint4 TA[8], TB[8];
    unsigned mskA = 0, mskB = 0;
    mskA = stageO1(TA, xb, h, wbase + P, g, 0);
    __builtin_amdgcn_sched_barrier(0);
    p1_tap(accO, TA, mskA, TB, mskB, xb, wofrag, h, wbase + P, g, l, 0, false);
    p1_tap(accO, TB, mskB, TA, mskA, xb, wofrag, h, wbase + P, g, l, 1, false);
    p1_tap(accO, TA, mskA, TB, mskB, xb, wofrag, h, wbase + P, g, l, 2, false);
    p1_tap(accO, TB, mskB, TA, mskA, xb, wofrag, h, wbase + P, g, l, 3, false);
    p1_tap(accO, TA, mskA, TB, mskB, xb, wofrag, h, wbase + P, g, l, 4, false);
    p1_tap(accO, TB, mskB, TA, mskA, xb, wofrag, h, wbase + P, g, l, 5, false);
    p1_tap(accO, TA, mskA, TB, mskB, xb, wofrag, h, wbase + P, g, l, 6, false);
    p1_tap(accO, TB, mskB, TA, mskA, xb, wofrag, h, wbase + P, g, l, 7, false);
    p1_tap(accO, TA, mskA, TB, mskB, xb, wofrag, h, wbase + P, g, l, 8, true);
    // park offsets in LDS: D layout col=P, row=(r&3)+8*(r>>2)+4g (validated)
#pragma unroll
    for (int r = 0; r < 16; ++r) {
      int oc = (r & 3) + 8 * (r >> 2) + 4 * g;
      if (oc < OCOFF) ol[P * OCOFF + oc] = accO[r] + b_off[oc];
    }
  }

  // ======================= PHASE 2: deformable conv ====================
  f32x16 acc0 = {0,0,0,0,0,0,0,0,0,0,0,0,0,0,0,0};
  f32x16 acc1 = {0,0,0,0,0,0,0,0,0,0,0,0,0,0,0,0};
  {
    float4 S0[8], S1[8], S2[8], S3[8];
    TapW t0, t1, t2, t3;
    t0 = stageD2(S0, xb, ol, h, wbase, pq, j4, 0, 0);
    __builtin_amdgcn_sched_barrier(0);
    t1 = stageD2(S1, xb, ol, h, wbase, pq, j4, 1, 0);
    __builtin_amdgcn_sched_barrier(0);
    p2_tap(acc0, acc1, S0, S1, S2, S3, t0, t1, t2, t3, mh, ml, xb, ol, wfrag,
           h, wbase, pq, j, j4, P, g, l, 0, false);
    p2_tap(acc0, acc1, S0, S1, S2, S3, t0, t1, t2, t3, mh, ml, xb, ol, wfrag,
           h, wbase, pq, j, j4, P, g, l, 1, false);
    p2_tap(acc0, acc1, S0, S1, S2, S3, t0, t1, t2, t3, mh, ml, xb, ol, wfrag,
           h, wbase, pq, j, j4, P, g, l, 2, false);
    p2_tap(acc0, acc1, S0, S1, S2, S3, t0, t1, t2, t3, mh, ml, xb, ol, wfrag,
           h, wbase, pq, j, j4, P, g, l, 3, false);
    p2_tap(acc0, acc1, S0, S1, S2, S3, t0, t1, t2, t3, mh, ml, xb, ol, wfrag,
           h, wbase, pq, j, j4, P, g, l, 4, false);
    p2_tap(acc0, acc1, S0, S1, S2, S3, t0, t1, t2, t3, mh, ml, xb, ol, wfrag,
           h, wbase, pq, j, j4, P, g, l, 5, false);
    p2_tap(acc0, acc1, S0, S1, S2, S3, t0, t1, t2, t3, mh, ml, xb, ol, wfrag,
           h, wbase, pq, j, j4, P, g, l, 6, false);
    p2_tap(acc0, acc1, S0, S1, S2, S3, t0, t1, t2, t3, mh, ml, xb, ol, wfrag,
           h, wbase, pq, j, j4, P, g, l, 7, false);
    p2_tap(acc0, acc1, S0, S1, S2, S3, t0, t1, t2, t3, mh, ml, xb, ol, wfrag,
           h, wbase, pq, j, j4, P, g, l, 8, true);
  }

  // epilogue: bias + store (validated layout)
  const int wpix = wbase + P;
#pragma unroll
  for (int r = 0; r < 16; ++r) {
    int o0 = (r & 3) + 8 * (r >> 2) + 4 * g;
    out[(((size_t)b * 64 + o0) * 128 + h) * 128 + wpix] = acc0[r] + bias[o0];
    out[(((size_t)b * 64 + 32 + o0) * 128 + h) * 128 + wpix] = acc1[r] + bias[32 + o0];
  }
}

// ---------------------------------------------------------------------------
extern "C" void kernel_launch(void* const* d_in, const int* in_sizes, int n_in,
                              void* d_out, int out_size, void* d_ws, size_t ws_size,
                              hipStream_t stream) {
  const float* x      = (const float*)d_in[0];
  const float* w_off  = (const float*)d_in[1];
  const float* b_off  = (const float*)d_in[2];
  const float* weight = (const float*)d_in[3];
  const float* bias   = (const float*)d_in[4];
  float* out = (float*)d_out;

  // workspace: xt | wfrag | wofrag  (~17 MB, proven)
  float*    xt     = (float*)d_ws;                       // 4,194,304 f
  unsigned* wfrag  = (unsigned*)(xt + (size_t)4194304);  // 36,864 dw
  unsigned* wofrag = wfrag + 36864;                      // 18,432 dw

  prep_all<<<2264, 256, 0, stream>>>(x, weight, w_off, xt, wfrag, wofrag);
  fused_deform<<<1024, 128, 0, stream>>>(xt, wfrag, wofrag, b_off, bias, out);
}